// Round 2
// baseline (11175.767 us; speedup 1.0000x reference)
//
#include <hip/hip_runtime.h>
#include <math.h>

#define NB 8
#define LFULL 1024
#define LVIS 512
#define NREL 3969

__device__ __forceinline__ float gelu_f(float x) {
    return 0.5f * x * (1.0f + erff(x * 0.7071067811865475f));
}

// ---------------- GEMM: C = A(M,K) @ W(N,K)^T + bias [+res | +gelu] ----------
// MODE: 0 = bias, 1 = bias + residual, 2 = bias + gelu
// M % 128 == 0, N % 64 == 0, K % 16 == 0
template<int MODE>
__global__ __launch_bounds__(256)
void gemm_nt(const float* __restrict__ A, const float* __restrict__ W,
             const float* __restrict__ bias, const float* res,
             float* C, int M, int N, int K)
{
    __shared__ float As[16][128];
    __shared__ float Ws[16][64];
    const int bm = blockIdx.y * 128;
    const int bn = blockIdx.x * 64;
    const int t  = threadIdx.x;
    const int tx = t & 15, ty = t >> 4;
    const int tm = ty * 8, tn = tx * 4;
    const int lr = t >> 2;          // 0..63
    const int lk = (t & 3) << 2;    // 0,4,8,12

    float acc[8][4];
#pragma unroll
    for (int i = 0; i < 8; ++i)
#pragma unroll
        for (int j = 0; j < 4; ++j) acc[i][j] = 0.0f;

    const float* pa0 = A + (size_t)(bm + lr) * K + lk;
    const float* pa1 = A + (size_t)(bm + 64 + lr) * K + lk;
    const float* pw  = W + (size_t)(bn + lr) * K + lk;

    for (int k0 = 0; k0 < K; k0 += 16) {
        const float4 a0 = *(const float4*)(pa0 + k0);
        const float4 a1 = *(const float4*)(pa1 + k0);
        const float4 w0 = *(const float4*)(pw  + k0);
        __syncthreads();
        As[lk + 0][lr] = a0.x; As[lk + 1][lr] = a0.y;
        As[lk + 2][lr] = a0.z; As[lk + 3][lr] = a0.w;
        As[lk + 0][64 + lr] = a1.x; As[lk + 1][64 + lr] = a1.y;
        As[lk + 2][64 + lr] = a1.z; As[lk + 3][64 + lr] = a1.w;
        Ws[lk + 0][lr] = w0.x; Ws[lk + 1][lr] = w0.y;
        Ws[lk + 2][lr] = w0.z; Ws[lk + 3][lr] = w0.w;
        __syncthreads();
#pragma unroll
        for (int k = 0; k < 16; ++k) {
            const float4 av0 = *(const float4*)&As[k][tm];
            const float4 av1 = *(const float4*)&As[k][tm + 4];
            const float4 wv  = *(const float4*)&Ws[k][tn];
            const float am[8] = {av0.x, av0.y, av0.z, av0.w, av1.x, av1.y, av1.z, av1.w};
            const float wn[4] = {wv.x, wv.y, wv.z, wv.w};
#pragma unroll
            for (int i = 0; i < 8; ++i)
#pragma unroll
                for (int j = 0; j < 4; ++j) acc[i][j] += am[i] * wn[j];
        }
    }

    const float b0 = bias[bn + tn + 0], b1 = bias[bn + tn + 1];
    const float b2 = bias[bn + tn + 2], b3 = bias[bn + tn + 3];
#pragma unroll
    for (int i = 0; i < 8; ++i) {
        const size_t row = (size_t)(bm + tm + i);
        float4 v = make_float4(acc[i][0] + b0, acc[i][1] + b1,
                               acc[i][2] + b2, acc[i][3] + b3);
        if (MODE == 1) {
            const float4 r4 = *(const float4*)(res + row * N + bn + tn);
            v.x += r4.x; v.y += r4.y; v.z += r4.z; v.w += r4.w;
        }
        if (MODE == 2) {
            v.x = gelu_f(v.x); v.y = gelu_f(v.y);
            v.z = gelu_f(v.z); v.w = gelu_f(v.w);
        }
        *(float4*)(C + row * N + bn + tn) = v;
    }
}

// ---------------- flash attention with relative-position bias ----------------
// qkv: (B, Lx, 3*Cx) with feature f = s*Cx + h*64 + d ; out: (B, Lx, Cx)
// grid: (Lx/64, H, B), block 256.  Per-thread: 4 q-rows x 4 cols.
template<bool HAS_IDX>
__global__ __launch_bounds__(256)
void attn_k(const float* __restrict__ qkv, const float* __restrict__ bt,
            const int* vis, float* __restrict__ out, int Lx, int Cx, int Hx)
{
    __shared__ float Qs[64][68];
    __shared__ float Ks[64][68];
    __shared__ float Vs[64][68];
    __shared__ float Ps[64][68];
    __shared__ int qidx[64], kidx[64];

    const int q0 = blockIdx.x * 64;
    const int h  = blockIdx.y;
    const int bb = blockIdx.z;
    const int t  = threadIdx.x;
    const int tx = t & 15, ty = t >> 4;
    const int r  = t >> 2, c4 = (t & 3) * 16;
    const int C3 = 3 * Cx;
    (void)vis;

    {   // load Q tile
        const float* src = qkv + (size_t)(bb * Lx + q0 + r) * C3 + h * 64 + c4;
#pragma unroll
        for (int u = 0; u < 4; ++u)
            *(float4*)&Qs[r][c4 + u * 4] = *(const float4*)(src + u * 4);
    }
    if (t < 64) qidx[t] = HAS_IDX ? vis[q0 + t] : (q0 + t);
    __syncthreads();

    int qi[4], qj[4];
#pragma unroll
    for (int i = 0; i < 4; ++i) {
        const int v = qidx[ty * 4 + i];
        qi[i] = v >> 5; qj[i] = v & 31;
    }

    float m_run[4], l_run[4];
    float4 Oa[4];
#pragma unroll
    for (int i = 0; i < 4; ++i) {
        m_run[i] = -INFINITY; l_run[i] = 0.0f;
        Oa[i] = make_float4(0.f, 0.f, 0.f, 0.f);
    }

    for (int k0 = 0; k0 < Lx; k0 += 64) {
        __syncthreads();
        {
            const float* ksrc = qkv + (size_t)(bb * Lx + k0 + r) * C3 + Cx + h * 64 + c4;
            const float* vsrc = qkv + (size_t)(bb * Lx + k0 + r) * C3 + 2 * Cx + h * 64 + c4;
#pragma unroll
            for (int u = 0; u < 4; ++u) {
                *(float4*)&Ks[r][c4 + u * 4] = *(const float4*)(ksrc + u * 4);
                *(float4*)&Vs[r][c4 + u * 4] = *(const float4*)(vsrc + u * 4);
            }
        }
        if (t < 64) kidx[t] = HAS_IDX ? vis[k0 + t] : (k0 + t);
        __syncthreads();

        // S = Q K^T   (4x4 per thread)
        float s4[4][4];
#pragma unroll
        for (int i = 0; i < 4; ++i)
#pragma unroll
            for (int j = 0; j < 4; ++j) s4[i][j] = 0.0f;
#pragma unroll
        for (int d0 = 0; d0 < 64; d0 += 4) {
            float4 qv[4], kv[4];
#pragma unroll
            for (int i = 0; i < 4; ++i) qv[i] = *(const float4*)&Qs[ty * 4 + i][d0];
#pragma unroll
            for (int j = 0; j < 4; ++j) kv[j] = *(const float4*)&Ks[tx * 4 + j][d0];
#pragma unroll
            for (int i = 0; i < 4; ++i)
#pragma unroll
                for (int j = 0; j < 4; ++j)
                    s4[i][j] += qv[i].x * kv[j].x + qv[i].y * kv[j].y +
                                qv[i].z * kv[j].z + qv[i].w * kv[j].w;
        }
        // scale + relative-position bias
#pragma unroll
        for (int j = 0; j < 4; ++j) {
            const int kvv = kidx[tx * 4 + j];
            const int ki = kvv >> 5, kj = kvv & 31;
#pragma unroll
            for (int i = 0; i < 4; ++i) {
                const int rel = (qi[i] - ki + 31) * 63 + (qj[i] - kj + 31);
                s4[i][j] = s4[i][j] * 0.125f + bt[rel * Hx + h];
            }
        }
        // online softmax (16 lanes with same ty share the q-row set)
#pragma unroll
        for (int i = 0; i < 4; ++i) {
            float mx = fmaxf(fmaxf(s4[i][0], s4[i][1]), fmaxf(s4[i][2], s4[i][3]));
#pragma unroll
            for (int off = 1; off < 16; off <<= 1) mx = fmaxf(mx, __shfl_xor(mx, off));
            const float mnew = fmaxf(m_run[i], mx);
            const float alpha = expf(m_run[i] - mnew);
            float rs = 0.0f;
#pragma unroll
            for (int j = 0; j < 4; ++j) {
                const float p = expf(s4[i][j] - mnew);
                s4[i][j] = p; rs += p;
            }
#pragma unroll
            for (int off = 1; off < 16; off <<= 1) rs += __shfl_xor(rs, off);
            l_run[i] = l_run[i] * alpha + rs;
            m_run[i] = mnew;
            Oa[i].x *= alpha; Oa[i].y *= alpha; Oa[i].z *= alpha; Oa[i].w *= alpha;
            *(float4*)&Ps[ty * 4 + i][tx * 4] = make_float4(s4[i][0], s4[i][1], s4[i][2], s4[i][3]);
        }
        __syncthreads();

        // O += P @ V
#pragma unroll
        for (int k4 = 0; k4 < 64; k4 += 4) {
            float4 pv[4], vr[4];
#pragma unroll
            for (int i = 0; i < 4; ++i) pv[i] = *(const float4*)&Ps[ty * 4 + i][k4];
#pragma unroll
            for (int u = 0; u < 4; ++u) vr[u] = *(const float4*)&Vs[k4 + u][tx * 4];
#pragma unroll
            for (int i = 0; i < 4; ++i) {
                Oa[i].x += pv[i].x * vr[0].x + pv[i].y * vr[1].x + pv[i].z * vr[2].x + pv[i].w * vr[3].x;
                Oa[i].y += pv[i].x * vr[0].y + pv[i].y * vr[1].y + pv[i].z * vr[2].y + pv[i].w * vr[3].y;
                Oa[i].z += pv[i].x * vr[0].z + pv[i].y * vr[1].z + pv[i].z * vr[2].z + pv[i].w * vr[3].z;
                Oa[i].w += pv[i].x * vr[0].w + pv[i].y * vr[1].w + pv[i].z * vr[2].w + pv[i].w * vr[3].w;
            }
        }
    }

#pragma unroll
    for (int i = 0; i < 4; ++i) {
        const float inv = 1.0f / l_run[i];
        float4 o = Oa[i];
        o.x *= inv; o.y *= inv; o.z *= inv; o.w *= inv;
        *(float4*)&out[(size_t)(bb * Lx + q0 + ty * 4 + i) * Cx + h * 64 + tx * 4] = o;
    }
}

// ---------------- LayerNorm (one block per row) ------------------------------
__global__ __launch_bounds__(256)
void ln_k(const float* __restrict__ x, const float* __restrict__ g,
          const float* __restrict__ be, float* __restrict__ y, int C)
{
    const int row = blockIdx.x;
    const float* xr = x + (size_t)row * C;
    float s = 0.f, ss = 0.f;
    for (int c = threadIdx.x; c < C; c += 256) { const float v = xr[c]; s += v; ss += v * v; }
#pragma unroll
    for (int off = 1; off < 64; off <<= 1) { s += __shfl_xor(s, off); ss += __shfl_xor(ss, off); }
    __shared__ float rs[4], rss[4];
    const int w = threadIdx.x >> 6;
    if ((threadIdx.x & 63) == 0) { rs[w] = s; rss[w] = ss; }
    __syncthreads();
    s  = rs[0] + rs[1] + rs[2] + rs[3];
    ss = rss[0] + rss[1] + rss[2] + rss[3];
    const float mean = s / C;
    const float rstd = rsqrtf(ss / C - mean * mean + 1e-5f);
    float* yr = y + (size_t)row * C;
    for (int c = threadIdx.x; c < C; c += 256)
        yr[c] = (xr[c] - mean) * rstd * g[c] + be[c];
}

// ---------------- glue kernels ----------------------------------------------
__global__ void gather_tokens_k(const float* __restrict__ x, const int* __restrict__ vis,
                                float* __restrict__ tok)
{
    const int id = blockIdx.x * 256 + threadIdx.x;     // NB*LVIS*128
    const int ti = id & 127;
    const int j  = (id >> 7) & 511;
    const int b  = id >> 16;
    const int l  = vis[j];
    const int hp = l >> 5, wp = l & 31;
    const int pi = ti >> 4, pj = (ti >> 1) & 7, ch = ti & 1;
    tok[id] = x[(((size_t)(b * 2 + ch) * 256) + hp * 8 + pi) * 256 + wp * 8 + pj];
}

__global__ void add_pos_vis_k(float* __restrict__ y, const float* __restrict__ pos,
                              const int* __restrict__ vis)
{
    const int id = blockIdx.x * 256 + threadIdx.x;     // NB*LVIS*768
    const int c = id % 768;
    const int j = (id / 768) & 511;
    y[id] += pos[(size_t)vis[j] * 768 + c];
}

__global__ void fill_dec_k(float* __restrict__ y, const float* __restrict__ mtok,
                           const float* __restrict__ pos)
{
    const int id = blockIdx.x * 256 + threadIdx.x;     // NB*LFULL*512
    const int c = id & 511;
    const int l = (id >> 9) & 1023;
    y[id] = mtok[c] + pos[(l << 9) + c];
}

__global__ void scatter_vis_k(float* __restrict__ y, const float* __restrict__ dvis,
                              const float* __restrict__ pos, const int* __restrict__ vis)
{
    const int id = blockIdx.x * 256 + threadIdx.x;     // NB*LVIS*512
    const int c = id & 511;
    const int j = (id >> 9) & 511;
    const int b = id >> 18;
    const int l = vis[j];
    y[(((size_t)b * 1024 + l) << 9) + c] = dvis[id] + pos[(l << 9) + c];
}

template<bool CLIP>
__global__ void unpatch_k(const float* __restrict__ tk, float* __restrict__ out)
{
    const int id = blockIdx.x * 256 + threadIdx.x;     // NB*65536
    const int j = id & 255, i = (id >> 8) & 255, b = id >> 16;
    const int hp = i >> 3, pi = i & 7, wp = j >> 3, pj = j & 7;
    float v = tk[((size_t)b * 1024 + hp * 32 + wp) * 64 + pi * 8 + pj];
    if (CLIP) v = fminf(6.0f, fmaxf(-6.0f, v));
    out[id] = v;
}

__global__ void mask_fill_k(float* m) { m[blockIdx.x * 256 + threadIdx.x] = 1.0f; }

__global__ void mask_zero_k(float* m, const int* __restrict__ vis)
{
    const int id = blockIdx.x * 256 + threadIdx.x;     // NB*LVIS
    const int b = id >> 9, j = id & 511;
    m[b * 1024 + vis[j]] = 0.0f;
}

// ---------------- launcher ---------------------------------------------------
extern "C" void kernel_launch(void* const* d_in, const int* in_sizes, int n_in,
                              void* d_out, int out_size, void* d_ws, size_t ws_size,
                              hipStream_t stream)
{
    const float* x       = (const float*)d_in[0];
    const int*   vis     = (const int*  )d_in[1];
    const float* eew     = (const float*)d_in[2];
    const float* eeb     = (const float*)d_in[3];
    const float* pos_enc = (const float*)d_in[4];
    const float* e_ln1s  = (const float*)d_in[5];
    const float* e_ln1b  = (const float*)d_in[6];
    const float* e_qkvw  = (const float*)d_in[7];
    const float* e_qkvb  = (const float*)d_in[8];
    const float* e_bt    = (const float*)d_in[9];
    const float* e_pw    = (const float*)d_in[10];
    const float* e_pb    = (const float*)d_in[11];
    const float* e_ln2s  = (const float*)d_in[12];
    const float* e_ln2b  = (const float*)d_in[13];
    const float* e_f1w   = (const float*)d_in[14];
    const float* e_f1b   = (const float*)d_in[15];
    const float* e_f2w   = (const float*)d_in[16];
    const float* e_f2b   = (const float*)d_in[17];
    const float* d_ln1s  = (const float*)d_in[18];
    const float* d_ln1b  = (const float*)d_in[19];
    const float* d_qkvw  = (const float*)d_in[20];
    const float* d_qkvb  = (const float*)d_in[21];
    const float* d_bt    = (const float*)d_in[22];
    const float* d_pw    = (const float*)d_in[23];
    const float* d_pb    = (const float*)d_in[24];
    const float* d_ln2s  = (const float*)d_in[25];
    const float* d_ln2b  = (const float*)d_in[26];
    const float* d_f1w   = (const float*)d_in[27];
    const float* d_f1b   = (const float*)d_in[28];
    const float* d_f2w   = (const float*)d_in[29];
    const float* d_f2b   = (const float*)d_in[30];
    const float* en_s    = (const float*)d_in[31];
    const float* en_b    = (const float*)d_in[32];
    const float* dew     = (const float*)d_in[33];
    const float* deb     = (const float*)d_in[34];
    const float* mtok    = (const float*)d_in[35];
    const float* pos_dec = (const float*)d_in[36];
    const float* dn_s    = (const float*)d_in[37];
    const float* dn_b    = (const float*)d_in[38];
    const float* hmw     = (const float*)d_in[39];
    const float* hmb     = (const float*)d_in[40];
    const float* hlw     = (const float*)d_in[41];
    const float* hlb     = (const float*)d_in[42];
    (void)in_sizes; (void)n_in; (void)out_size; (void)ws_size;

    float* ws   = (float*)d_ws;
    float* bx   = ws;                 // activations   (<= 4,194,304 f)
    float* bh   = ws + 4194304;       // LN output     (<= 4,194,304 f)
    float* batt = ws + 8388608;       // attn out / dec_vis (<= 4,194,304 f)
    float* bbig = ws + 12582912;      // qkv / mlp-hid / tokens / head out (<= 16,777,216 f)

    // ---- patchify(visible) + encoder embed + pos ----
    gather_tokens_k<<<NB * LVIS * 128 / 256, 256, 0, stream>>>(x, vis, bbig);
    gemm_nt<0><<<dim3(12, 32), 256, 0, stream>>>(bbig, eew, eeb, nullptr, bx, 4096, 768, 128);
    add_pos_vis_k<<<NB * LVIS * 768 / 256, 256, 0, stream>>>(bx, pos_enc, vis);

    // ---- encoder blocks ----
    for (int d = 0; d < 6; ++d) {
        ln_k<<<4096, 256, 0, stream>>>(bx, e_ln1s + d * 768, e_ln1b + d * 768, bh, 768);
        gemm_nt<0><<<dim3(36, 32), 256, 0, stream>>>(bh, e_qkvw + (size_t)d * 2304 * 768,
                                                     e_qkvb + d * 2304, nullptr, bbig, 4096, 2304, 768);
        attn_k<true><<<dim3(8, 12, NB), 256, 0, stream>>>(bbig, e_bt + (size_t)d * NREL * 12,
                                                          vis, batt, 512, 768, 12);
        gemm_nt<1><<<dim3(12, 32), 256, 0, stream>>>(batt, e_pw + (size_t)d * 768 * 768,
                                                     e_pb + d * 768, bx, bx, 4096, 768, 768);
        ln_k<<<4096, 256, 0, stream>>>(bx, e_ln2s + d * 768, e_ln2b + d * 768, bh, 768);
        gemm_nt<2><<<dim3(48, 32), 256, 0, stream>>>(bh, e_f1w + (size_t)d * 3072 * 768,
                                                     e_f1b + d * 3072, nullptr, bbig, 4096, 3072, 768);
        gemm_nt<1><<<dim3(12, 32), 256, 0, stream>>>(bbig, e_f2w + (size_t)d * 768 * 3072,
                                                     e_f2b + d * 768, bx, bx, 4096, 768, 3072);
    }

    // ---- encoder norm + decoder embed + sequence build ----
    ln_k<<<4096, 256, 0, stream>>>(bx, en_s, en_b, bh, 768);
    gemm_nt<0><<<dim3(8, 32), 256, 0, stream>>>(bh, dew, deb, nullptr, batt, 4096, 512, 768);
    fill_dec_k<<<NB * LFULL * 512 / 256, 256, 0, stream>>>(bx, mtok, pos_dec);
    scatter_vis_k<<<NB * LVIS * 512 / 256, 256, 0, stream>>>(bx, batt, pos_dec, vis);

    // ---- decoder blocks ----
    for (int d = 0; d < 4; ++d) {
        ln_k<<<8192, 256, 0, stream>>>(bx, d_ln1s + d * 512, d_ln1b + d * 512, bh, 512);
        gemm_nt<0><<<dim3(24, 64), 256, 0, stream>>>(bh, d_qkvw + (size_t)d * 1536 * 512,
                                                     d_qkvb + d * 1536, nullptr, bbig, 8192, 1536, 512);
        attn_k<false><<<dim3(16, 8, NB), 256, 0, stream>>>(bbig, d_bt + (size_t)d * NREL * 8,
                                                           nullptr, batt, 1024, 512, 8);
        gemm_nt<1><<<dim3(8, 64), 256, 0, stream>>>(batt, d_pw + (size_t)d * 512 * 512,
                                                    d_pb + d * 512, bx, bx, 8192, 512, 512);
        ln_k<<<8192, 256, 0, stream>>>(bx, d_ln2s + d * 512, d_ln2b + d * 512, bh, 512);
        gemm_nt<2><<<dim3(32, 64), 256, 0, stream>>>(bh, d_f1w + (size_t)d * 2048 * 512,
                                                     d_f1b + d * 2048, nullptr, bbig, 8192, 2048, 512);
        gemm_nt<1><<<dim3(8, 64), 256, 0, stream>>>(bbig, d_f2w + (size_t)d * 512 * 2048,
                                                    d_f2b + d * 512, bx, bx, 8192, 512, 2048);
    }

    // ---- final norm + heads + unpatchify + mask ----
    ln_k<<<8192, 256, 0, stream>>>(bx, dn_s, dn_b, bh, 512);
    float* mu_tok = bbig;
    float* lv_tok = bbig + 524288;
    gemm_nt<0><<<dim3(1, 64), 256, 0, stream>>>(bh, hmw, hmb, nullptr, mu_tok, 8192, 64, 512);
    gemm_nt<0><<<dim3(1, 64), 256, 0, stream>>>(bh, hlw, hlb, nullptr, lv_tok, 8192, 64, 512);

    float* out = (float*)d_out;
    unpatch_k<false><<<NB * 65536 / 256, 256, 0, stream>>>(mu_tok, out);
    unpatch_k<true ><<<NB * 65536 / 256, 256, 0, stream>>>(lv_tok, out + 524288);
    mask_fill_k<<<32, 256, 0, stream>>>(out + 1048576);
    mask_zero_k<<<16, 256, 0, stream>>>(out + 1048576, vis);
}

// Round 3
// 4602.735 us; speedup vs baseline: 2.4281x; 2.4281x over previous
//
#include <hip/hip_runtime.h>
#include <math.h>

#define NB 8
#define LFULL 1024
#define LVIS 512
#define NREL 3969

typedef __attribute__((ext_vector_type(8))) short s8v;
typedef __attribute__((ext_vector_type(4))) float f4v;

__device__ __forceinline__ float gelu_f(float x) {
    return 0.5f * x * (1.0f + erff(x * 0.7071067811865475f));
}

// fp32 -> bf16 (round-to-nearest-even), bit pattern in a short
__device__ __forceinline__ short f2bf(float x) {
    union { float f; unsigned u; } v; v.f = x;
    unsigned r = v.u + 0x7FFFu + ((v.u >> 16) & 1u);
    return (short)(r >> 16);
}

// ============ bf16 MFMA GEMM: C = A(M,K) @ W(N,K)^T + bias [+res|+gelu] ======
// MODE: 0 bias, 1 bias+residual, 2 bias+gelu.  M%128==0, N%128==0, K%32==0.
// 256 thr = 4 waves; block tile 128x128; wave tile 64x64 (4x4 frags 16x16x32).
template<int MODE>
__global__ __launch_bounds__(256)
void gemm_bf16(const float* __restrict__ A, const float* __restrict__ W,
               const float* __restrict__ bias, const float* res,
               float* __restrict__ C, int M, int N, int K)
{
    __shared__ __align__(16) short Al[8][64][8];   // [frag][lane][8] fragment-linear
    __shared__ __align__(16) short Wl[8][64][8];
    const int t  = threadIdx.x;
    const int w  = t >> 6, l = t & 63;
    const int lg = l >> 4, lr = l & 15;
    const int bm = blockIdx.y * 128, bn = blockIdx.x * 128;
    const int wm = (w & 1) * 64,  wn = (w >> 1) * 64;

    f4v acc[4][4];
#pragma unroll
    for (int i = 0; i < 4; ++i)
#pragma unroll
        for (int j = 0; j < 4; ++j) acc[i][j] = (f4v){0.f, 0.f, 0.f, 0.f};

    const int srow = t >> 1;            // 0..127
    const int kh   = (t & 1) * 16;      // 0 or 16
    const float* pa = A + (size_t)(bm + srow) * K + kh;
    const float* pw = W + (size_t)(bn + srow) * K + kh;

    for (int k0 = 0; k0 < K; k0 += 32) {
        float4 a0 = *(const float4*)(pa + k0),     a1 = *(const float4*)(pa + k0 + 4);
        float4 a2 = *(const float4*)(pa + k0 + 8), a3 = *(const float4*)(pa + k0 + 12);
        float4 w0 = *(const float4*)(pw + k0),     w1 = *(const float4*)(pw + k0 + 4);
        float4 w2 = *(const float4*)(pw + k0 + 8), w3 = *(const float4*)(pw + k0 + 12);
        __syncthreads();
        {
            s8v p0, p1;
            p0[0]=f2bf(a0.x); p0[1]=f2bf(a0.y); p0[2]=f2bf(a0.z); p0[3]=f2bf(a0.w);
            p0[4]=f2bf(a1.x); p0[5]=f2bf(a1.y); p0[6]=f2bf(a1.z); p0[7]=f2bf(a1.w);
            p1[0]=f2bf(a2.x); p1[1]=f2bf(a2.y); p1[2]=f2bf(a2.z); p1[3]=f2bf(a2.w);
            p1[4]=f2bf(a3.x); p1[5]=f2bf(a3.y); p1[6]=f2bf(a3.z); p1[7]=f2bf(a3.w);
            const int ln0 = (srow & 15) + 16 * (2 * (t & 1) + 0);
            const int ln1 = (srow & 15) + 16 * (2 * (t & 1) + 1);
            *(s8v*)&Al[srow >> 4][ln0][0] = p0;
            *(s8v*)&Al[srow >> 4][ln1][0] = p1;
            p0[0]=f2bf(w0.x); p0[1]=f2bf(w0.y); p0[2]=f2bf(w0.z); p0[3]=f2bf(w0.w);
            p0[4]=f2bf(w1.x); p0[5]=f2bf(w1.y); p0[6]=f2bf(w1.z); p0[7]=f2bf(w1.w);
            p1[0]=f2bf(w2.x); p1[1]=f2bf(w2.y); p1[2]=f2bf(w2.z); p1[3]=f2bf(w2.w);
            p1[4]=f2bf(w3.x); p1[5]=f2bf(w3.y); p1[6]=f2bf(w3.z); p1[7]=f2bf(w3.w);
            *(s8v*)&Wl[srow >> 4][ln0][0] = p0;
            *(s8v*)&Wl[srow >> 4][ln1][0] = p1;
        }
        __syncthreads();
        s8v af[4], bf[4];
#pragma unroll
        for (int mi = 0; mi < 4; ++mi) af[mi] = *(const s8v*)&Al[(wm >> 4) + mi][l][0];
#pragma unroll
        for (int ni = 0; ni < 4; ++ni) bf[ni] = *(const s8v*)&Wl[(wn >> 4) + ni][l][0];
#pragma unroll
        for (int mi = 0; mi < 4; ++mi)
#pragma unroll
            for (int ni = 0; ni < 4; ++ni)
                acc[mi][ni] = __builtin_amdgcn_mfma_f32_16x16x32_bf16(af[mi], bf[ni], acc[mi][ni], 0, 0, 0);
    }

    // epilogue: C row = bm+wm+mi*16+lg*4+r , col = bn+wn+ni*16+lr
#pragma unroll
    for (int ni = 0; ni < 4; ++ni) {
        const int col = bn + wn + ni * 16 + lr;
        const float bb = bias[col];
#pragma unroll
        for (int mi = 0; mi < 4; ++mi) {
#pragma unroll
            for (int r = 0; r < 4; ++r) {
                const int rowg = bm + wm + mi * 16 + lg * 4 + r;
                float v = acc[mi][ni][r] + bb;
                if (MODE == 1) v += res[(size_t)rowg * N + col];
                if (MODE == 2) v = gelu_f(v);
                C[(size_t)rowg * N + col] = v;
            }
        }
    }
}

// ---------------- fp32 GEMM (kept for N=64 heads) ---------------------------
template<int MODE>
__global__ __launch_bounds__(256)
void gemm_nt(const float* __restrict__ A, const float* __restrict__ W,
             const float* __restrict__ bias, const float* res,
             float* C, int M, int N, int K)
{
    __shared__ float As[16][128];
    __shared__ float Ws[16][64];
    const int bm = blockIdx.y * 128;
    const int bn = blockIdx.x * 64;
    const int t  = threadIdx.x;
    const int tx = t & 15, ty = t >> 4;
    const int tm = ty * 8, tn = tx * 4;
    const int lr = t >> 2;
    const int lk = (t & 3) << 2;

    float acc[8][4];
#pragma unroll
    for (int i = 0; i < 8; ++i)
#pragma unroll
        for (int j = 0; j < 4; ++j) acc[i][j] = 0.0f;

    const float* pa0 = A + (size_t)(bm + lr) * K + lk;
    const float* pa1 = A + (size_t)(bm + 64 + lr) * K + lk;
    const float* pw  = W + (size_t)(bn + lr) * K + lk;

    for (int k0 = 0; k0 < K; k0 += 16) {
        const float4 a0 = *(const float4*)(pa0 + k0);
        const float4 a1 = *(const float4*)(pa1 + k0);
        const float4 w0 = *(const float4*)(pw  + k0);
        __syncthreads();
        As[lk + 0][lr] = a0.x; As[lk + 1][lr] = a0.y;
        As[lk + 2][lr] = a0.z; As[lk + 3][lr] = a0.w;
        As[lk + 0][64 + lr] = a1.x; As[lk + 1][64 + lr] = a1.y;
        As[lk + 2][64 + lr] = a1.z; As[lk + 3][64 + lr] = a1.w;
        Ws[lk + 0][lr] = w0.x; Ws[lk + 1][lr] = w0.y;
        Ws[lk + 2][lr] = w0.z; Ws[lk + 3][lr] = w0.w;
        __syncthreads();
#pragma unroll
        for (int k = 0; k < 16; ++k) {
            const float4 av0 = *(const float4*)&As[k][tm];
            const float4 av1 = *(const float4*)&As[k][tm + 4];
            const float4 wv  = *(const float4*)&Ws[k][tn];
            const float am[8] = {av0.x, av0.y, av0.z, av0.w, av1.x, av1.y, av1.z, av1.w};
            const float wn4[4] = {wv.x, wv.y, wv.z, wv.w};
#pragma unroll
            for (int i = 0; i < 8; ++i)
#pragma unroll
                for (int j = 0; j < 4; ++j) acc[i][j] += am[i] * wn4[j];
        }
    }

    const float b0 = bias[bn + tn + 0], b1 = bias[bn + tn + 1];
    const float b2 = bias[bn + tn + 2], b3 = bias[bn + tn + 3];
#pragma unroll
    for (int i = 0; i < 8; ++i) {
        const size_t row = (size_t)(bm + tm + i);
        float4 v = make_float4(acc[i][0] + b0, acc[i][1] + b1,
                               acc[i][2] + b2, acc[i][3] + b3);
        if (MODE == 1) {
            const float4 r4 = *(const float4*)(res + row * N + bn + tn);
            v.x += r4.x; v.y += r4.y; v.z += r4.z; v.w += r4.w;
        }
        if (MODE == 2) {
            v.x = gelu_f(v.x); v.y = gelu_f(v.y);
            v.z = gelu_f(v.z); v.w = gelu_f(v.w);
        }
        *(float4*)(C + row * N + bn + tn) = v;
    }
}

// ============ MFMA flash attention with relative-position bias ===============
// qkv: (B,Lx,3*Cx), f = s*Cx + h*64 + d.  grid (Lx/64, H, B), 256 thr = 4 waves.
// Wave w owns q rows [q0+16w, q0+16w+16). K-tile = 32 keys.
template<bool HAS_IDX>
__global__ __launch_bounds__(256)
void attn_mfma(const float* __restrict__ qkv, const float* __restrict__ bt,
               const int* vis, float* __restrict__ out, int Lx, int Cx, int Hx)
{
    __shared__ __align__(16) short Kl[32][72];      // [key][d]   stride 144B
    __shared__ __align__(16) short Vl[64][40];      // [d][key]   stride 80B
    __shared__ __align__(16) short Pl[4][16][40];   // per-wave [q][key]
    __shared__ int qidx_s[64];
    __shared__ int kidx_s[32];

    const int q0 = blockIdx.x * 64;
    const int h  = blockIdx.y, bb = blockIdx.z;
    const int t  = threadIdx.x;
    const int w  = t >> 6, l = t & 63;
    const int lg = l >> 4, lr = l & 15;
    const int C3 = 3 * Cx;

    // Q fragments in registers (fp32 -> bf16): A-frag (row=lr, k=lg*8+e), 2 d-chunks
    s8v qa[2];
    {
        const int q = q0 + w * 16 + lr;
        const float* src = qkv + (size_t)(bb * Lx + q) * C3 + h * 64 + lg * 8;
#pragma unroll
        for (int c = 0; c < 2; ++c) {
            float4 x0 = *(const float4*)(src + c * 32);
            float4 x1 = *(const float4*)(src + c * 32 + 4);
            s8v v;
            v[0]=f2bf(x0.x); v[1]=f2bf(x0.y); v[2]=f2bf(x0.z); v[3]=f2bf(x0.w);
            v[4]=f2bf(x1.x); v[5]=f2bf(x1.y); v[6]=f2bf(x1.z); v[7]=f2bf(x1.w);
            qa[c] = v;
        }
    }
    if (t < 64) qidx_s[t] = HAS_IDX ? vis[q0 + t] : (q0 + t);
    __syncthreads();

    int qi[4], qj[4];
#pragma unroll
    for (int r = 0; r < 4; ++r) {
        const int v = qidx_s[w * 16 + lg * 4 + r];
        qi[r] = v >> 5; qj[r] = v & 31;
    }

    float m_run[4], l_run[4];
    f4v o[4];
#pragma unroll
    for (int r = 0; r < 4; ++r) { m_run[r] = -INFINITY; l_run[r] = 0.0f; }
#pragma unroll
    for (int df = 0; df < 4; ++df) o[df] = (f4v){0.f, 0.f, 0.f, 0.f};

    const int nt = Lx >> 5;
    for (int kt = 0; kt < nt; ++kt) {
        __syncthreads();
        {   // stage K tile: [key][d] bf16, thread: key=t>>3, dh=(t&7)*8
            const int key = t >> 3, dh = (t & 7) * 8;
            const float* src = qkv + (size_t)(bb * Lx + kt * 32 + key) * C3 + Cx + h * 64 + dh;
            float4 x0 = *(const float4*)src, x1 = *(const float4*)(src + 4);
            s8v v;
            v[0]=f2bf(x0.x); v[1]=f2bf(x0.y); v[2]=f2bf(x0.z); v[3]=f2bf(x0.w);
            v[4]=f2bf(x1.x); v[5]=f2bf(x1.y); v[6]=f2bf(x1.z); v[7]=f2bf(x1.w);
            *(s8v*)&Kl[key][dh] = v;
        }
        {   // stage V tile transposed: [d][key], thread: key=t&31, dh=(t>>5)*8
            const int key = t & 31, dh = (t >> 5) * 8;
            const float* src = qkv + (size_t)(bb * Lx + kt * 32 + key) * C3 + 2 * Cx + h * 64 + dh;
            float4 x0 = *(const float4*)src, x1 = *(const float4*)(src + 4);
            Vl[dh + 0][key] = f2bf(x0.x); Vl[dh + 1][key] = f2bf(x0.y);
            Vl[dh + 2][key] = f2bf(x0.z); Vl[dh + 3][key] = f2bf(x0.w);
            Vl[dh + 4][key] = f2bf(x1.x); Vl[dh + 5][key] = f2bf(x1.y);
            Vl[dh + 6][key] = f2bf(x1.z); Vl[dh + 7][key] = f2bf(x1.w);
        }
        if (t < 32) kidx_s[t] = HAS_IDX ? vis[kt * 32 + t] : (kt * 32 + t);
        __syncthreads();

        // S = Q K^T : 2 key-half frags x 2 d-chunks
        f4v s[2];
        s[0] = (f4v){0.f,0.f,0.f,0.f}; s[1] = (f4v){0.f,0.f,0.f,0.f};
#pragma unroll
        for (int f = 0; f < 2; ++f)
#pragma unroll
            for (int c = 0; c < 2; ++c) {
                s8v kb = *(const s8v*)&Kl[lr + 16 * f][c * 32 + lg * 8];
                s[f] = __builtin_amdgcn_mfma_f32_16x16x32_bf16(qa[c], kb, s[f], 0, 0, 0);
            }

        // bias + online softmax.  C-layout: row q = lg*4+r, col key = lr+16f
        const int kv0 = kidx_s[lr],      ki0 = kv0 >> 5, kj0 = kv0 & 31;
        const int kv1 = kidx_s[lr + 16], ki1 = kv1 >> 5, kj1 = kv1 & 31;
#pragma unroll
        for (int r = 0; r < 4; ++r) {
            const float b0 = bt[(size_t)((qi[r] - ki0 + 31) * 63 + (qj[r] - kj0 + 31)) * Hx + h];
            const float b1 = bt[(size_t)((qi[r] - ki1 + 31) * 63 + (qj[r] - kj1 + 31)) * Hx + h];
            float v0 = s[0][r] * 0.125f + b0;
            float v1 = s[1][r] * 0.125f + b1;
            float mx = fmaxf(v0, v1);
#pragma unroll
            for (int off = 1; off < 16; off <<= 1) mx = fmaxf(mx, __shfl_xor(mx, off));
            const float mnew = fmaxf(m_run[r], mx);
            const float alpha = expf(m_run[r] - mnew);
            const float p0 = expf(v0 - mnew), p1 = expf(v1 - mnew);
            float rs = p0 + p1;
#pragma unroll
            for (int off = 1; off < 16; off <<= 1) rs += __shfl_xor(rs, off);
            l_run[r] = l_run[r] * alpha + rs;
            m_run[r] = mnew;
            o[0][r] *= alpha; o[1][r] *= alpha; o[2][r] *= alpha; o[3][r] *= alpha;
            Pl[w][lg * 4 + r][lr]      = f2bf(p0);
            Pl[w][lg * 4 + r][lr + 16] = f2bf(p1);
        }
        __syncthreads();

        // O += P V : A-frag P (row=lr, k=lg*8+e), B-frag V (col=lr, k=lg*8+e)
        s8v pa = *(const s8v*)&Pl[w][lr][lg * 8];
#pragma unroll
        for (int df = 0; df < 4; ++df) {
            s8v vb = *(const s8v*)&Vl[df * 16 + lr][lg * 8];
            o[df] = __builtin_amdgcn_mfma_f32_16x16x32_bf16(pa, vb, o[df], 0, 0, 0);
        }
    }

    float invl[4];
#pragma unroll
    for (int r = 0; r < 4; ++r) invl[r] = 1.0f / l_run[r];
#pragma unroll
    for (int df = 0; df < 4; ++df)
#pragma unroll
        for (int r = 0; r < 4; ++r)
            out[(size_t)(bb * Lx + q0 + w * 16 + lg * 4 + r) * Cx + h * 64 + df * 16 + lr] =
                o[df][r] * invl[r];
}

// ---------------- LayerNorm (one block per row) ------------------------------
__global__ __launch_bounds__(256)
void ln_k(const float* __restrict__ x, const float* __restrict__ g,
          const float* __restrict__ be, float* __restrict__ y, int C)
{
    const int row = blockIdx.x;
    const float* xr = x + (size_t)row * C;
    float s = 0.f, ss = 0.f;
    for (int c = threadIdx.x; c < C; c += 256) { const float v = xr[c]; s += v; ss += v * v; }
#pragma unroll
    for (int off = 1; off < 64; off <<= 1) { s += __shfl_xor(s, off); ss += __shfl_xor(ss, off); }
    __shared__ float rs[4], rss[4];
    const int w = threadIdx.x >> 6;
    if ((threadIdx.x & 63) == 0) { rs[w] = s; rss[w] = ss; }
    __syncthreads();
    s  = rs[0] + rs[1] + rs[2] + rs[3];
    ss = rss[0] + rss[1] + rss[2] + rss[3];
    const float mean = s / C;
    const float rstd = rsqrtf(ss / C - mean * mean + 1e-5f);
    float* yr = y + (size_t)row * C;
    for (int c = threadIdx.x; c < C; c += 256)
        yr[c] = (xr[c] - mean) * rstd * g[c] + be[c];
}

// ---------------- glue kernels ----------------------------------------------
__global__ void gather_tokens_k(const float* __restrict__ x, const int* __restrict__ vis,
                                float* __restrict__ tok)
{
    const int id = blockIdx.x * 256 + threadIdx.x;
    const int ti = id & 127;
    const int j  = (id >> 7) & 511;
    const int b  = id >> 16;
    const int ll = vis[j];
    const int hp = ll >> 5, wp = ll & 31;
    const int pi = ti >> 4, pj = (ti >> 1) & 7, ch = ti & 1;
    tok[id] = x[(((size_t)(b * 2 + ch) * 256) + hp * 8 + pi) * 256 + wp * 8 + pj];
}

__global__ void add_pos_vis_k(float* __restrict__ y, const float* __restrict__ pos,
                              const int* __restrict__ vis)
{
    const int id = blockIdx.x * 256 + threadIdx.x;
    const int c = id % 768;
    const int j = (id / 768) & 511;
    y[id] += pos[(size_t)vis[j] * 768 + c];
}

__global__ void fill_dec_k(float* __restrict__ y, const float* __restrict__ mtok,
                           const float* __restrict__ pos)
{
    const int id = blockIdx.x * 256 + threadIdx.x;
    const int c = id & 511;
    const int ll = (id >> 9) & 1023;
    y[id] = mtok[c] + pos[(ll << 9) + c];
}

__global__ void scatter_vis_k(float* __restrict__ y, const float* __restrict__ dvis,
                              const float* __restrict__ pos, const int* __restrict__ vis)
{
    const int id = blockIdx.x * 256 + threadIdx.x;
    const int c = id & 511;
    const int j = (id >> 9) & 511;
    const int b = id >> 18;
    const int ll = vis[j];
    y[(((size_t)b * 1024 + ll) << 9) + c] = dvis[id] + pos[(ll << 9) + c];
}

template<bool CLIP>
__global__ void unpatch_k(const float* __restrict__ tk, float* __restrict__ out)
{
    const int id = blockIdx.x * 256 + threadIdx.x;
    const int j = id & 255, i = (id >> 8) & 255, b = id >> 16;
    const int hp = i >> 3, pi = i & 7, wp = j >> 3, pj = j & 7;
    float v = tk[((size_t)b * 1024 + hp * 32 + wp) * 64 + pi * 8 + pj];
    if (CLIP) v = fminf(6.0f, fmaxf(-6.0f, v));
    out[id] = v;
}

__global__ void mask_fill_k(float* m) { m[blockIdx.x * 256 + threadIdx.x] = 1.0f; }

__global__ void mask_zero_k(float* m, const int* __restrict__ vis)
{
    const int id = blockIdx.x * 256 + threadIdx.x;
    const int b = id >> 9, j = id & 511;
    m[b * 1024 + vis[j]] = 0.0f;
}

// ---------------- launcher ---------------------------------------------------
extern "C" void kernel_launch(void* const* d_in, const int* in_sizes, int n_in,
                              void* d_out, int out_size, void* d_ws, size_t ws_size,
                              hipStream_t stream)
{
    const float* x       = (const float*)d_in[0];
    const int*   vis     = (const int*  )d_in[1];
    const float* eew     = (const float*)d_in[2];
    const float* eeb     = (const float*)d_in[3];
    const float* pos_enc = (const float*)d_in[4];
    const float* e_ln1s  = (const float*)d_in[5];
    const float* e_ln1b  = (const float*)d_in[6];
    const float* e_qkvw  = (const float*)d_in[7];
    const float* e_qkvb  = (const float*)d_in[8];
    const float* e_bt    = (const float*)d_in[9];
    const float* e_pw    = (const float*)d_in[10];
    const float* e_pb    = (const float*)d_in[11];
    const float* e_ln2s  = (const float*)d_in[12];
    const float* e_ln2b  = (const float*)d_in[13];
    const float* e_f1w   = (const float*)d_in[14];
    const float* e_f1b   = (const float*)d_in[15];
    const float* e_f2w   = (const float*)d_in[16];
    const float* e_f2b   = (const float*)d_in[17];
    const float* d_ln1s  = (const float*)d_in[18];
    const float* d_ln1b  = (const float*)d_in[19];
    const float* d_qkvw  = (const float*)d_in[20];
    const float* d_qkvb  = (const float*)d_in[21];
    const float* d_bt    = (const float*)d_in[22];
    const float* d_pw    = (const float*)d_in[23];
    const float* d_pb    = (const float*)d_in[24];
    const float* d_ln2s  = (const float*)d_in[25];
    const float* d_ln2b  = (const float*)d_in[26];
    const float* d_f1w   = (const float*)d_in[27];
    const float* d_f1b   = (const float*)d_in[28];
    const float* d_f2w   = (const float*)d_in[29];
    const float* d_f2b   = (const float*)d_in[30];
    const float* en_s    = (const float*)d_in[31];
    const float* en_b    = (const float*)d_in[32];
    const float* dew     = (const float*)d_in[33];
    const float* deb     = (const float*)d_in[34];
    const float* mtok    = (const float*)d_in[35];
    const float* pos_dec = (const float*)d_in[36];
    const float* dn_s    = (const float*)d_in[37];
    const float* dn_b    = (const float*)d_in[38];
    const float* hmw     = (const float*)d_in[39];
    const float* hmb     = (const float*)d_in[40];
    const float* hlw     = (const float*)d_in[41];
    const float* hlb     = (const float*)d_in[42];
    (void)in_sizes; (void)n_in; (void)out_size; (void)ws_size;

    float* ws   = (float*)d_ws;
    float* bx   = ws;                 // activations
    float* bh   = ws + 4194304;       // LN output
    float* batt = ws + 8388608;       // attn out / dec_vis
    float* bbig = ws + 12582912;      // qkv / mlp hidden / tokens / head out

    // ---- patchify(visible) + encoder embed + pos ----
    gather_tokens_k<<<NB * LVIS * 128 / 256, 256, 0, stream>>>(x, vis, bbig);
    gemm_bf16<0><<<dim3(6, 32), 256, 0, stream>>>(bbig, eew, eeb, nullptr, bx, 4096, 768, 128);
    add_pos_vis_k<<<NB * LVIS * 768 / 256, 256, 0, stream>>>(bx, pos_enc, vis);

    // ---- encoder blocks ----
    for (int d = 0; d < 6; ++d) {
        ln_k<<<4096, 256, 0, stream>>>(bx, e_ln1s + d * 768, e_ln1b + d * 768, bh, 768);
        gemm_bf16<0><<<dim3(18, 32), 256, 0, stream>>>(bh, e_qkvw + (size_t)d * 2304 * 768,
                                                       e_qkvb + d * 2304, nullptr, bbig, 4096, 2304, 768);
        attn_mfma<true><<<dim3(8, 12, NB), 256, 0, stream>>>(bbig, e_bt + (size_t)d * NREL * 12,
                                                             vis, batt, 512, 768, 12);
        gemm_bf16<1><<<dim3(6, 32), 256, 0, stream>>>(batt, e_pw + (size_t)d * 768 * 768,
                                                      e_pb + d * 768, bx, bx, 4096, 768, 768);
        ln_k<<<4096, 256, 0, stream>>>(bx, e_ln2s + d * 768, e_ln2b + d * 768, bh, 768);
        gemm_bf16<2><<<dim3(24, 32), 256, 0, stream>>>(bh, e_f1w + (size_t)d * 3072 * 768,
                                                       e_f1b + d * 3072, nullptr, bbig, 4096, 3072, 768);
        gemm_bf16<1><<<dim3(6, 32), 256, 0, stream>>>(bbig, e_f2w + (size_t)d * 768 * 3072,
                                                      e_f2b + d * 768, bx, bx, 4096, 768, 3072);
    }

    // ---- encoder norm + decoder embed + sequence build ----
    ln_k<<<4096, 256, 0, stream>>>(bx, en_s, en_b, bh, 768);
    gemm_bf16<0><<<dim3(4, 32), 256, 0, stream>>>(bh, dew, deb, nullptr, batt, 4096, 512, 768);
    fill_dec_k<<<NB * LFULL * 512 / 256, 256, 0, stream>>>(bx, mtok, pos_dec);
    scatter_vis_k<<<NB * LVIS * 512 / 256, 256, 0, stream>>>(bx, batt, pos_dec, vis);

    // ---- decoder blocks ----
    for (int d = 0; d < 4; ++d) {
        ln_k<<<8192, 256, 0, stream>>>(bx, d_ln1s + d * 512, d_ln1b + d * 512, bh, 512);
        gemm_bf16<0><<<dim3(12, 64), 256, 0, stream>>>(bh, d_qkvw + (size_t)d * 1536 * 512,
                                                       d_qkvb + d * 1536, nullptr, bbig, 8192, 1536, 512);
        attn_mfma<false><<<dim3(16, 8, NB), 256, 0, stream>>>(bbig, d_bt + (size_t)d * NREL * 8,
                                                              nullptr, batt, 1024, 512, 8);
        gemm_bf16<1><<<dim3(4, 64), 256, 0, stream>>>(batt, d_pw + (size_t)d * 512 * 512,
                                                      d_pb + d * 512, bx, bx, 8192, 512, 512);
        ln_k<<<8192, 256, 0, stream>>>(bx, d_ln2s + d * 512, d_ln2b + d * 512, bh, 512);
        gemm_bf16<2><<<dim3(16, 64), 256, 0, stream>>>(bh, d_f1w + (size_t)d * 2048 * 512,
                                                       d_f1b + d * 2048, nullptr, bbig, 8192, 2048, 512);
        gemm_bf16<1><<<dim3(4, 64), 256, 0, stream>>>(bbig, d_f2w + (size_t)d * 512 * 2048,
                                                      d_f2b + d * 512, bx, bx, 8192, 512, 2048);
    }

    // ---- final norm + heads + unpatchify + mask ----
    ln_k<<<8192, 256, 0, stream>>>(bx, dn_s, dn_b, bh, 512);
    float* mu_tok = bbig;
    float* lv_tok = bbig + 524288;
    gemm_nt<0><<<dim3(1, 64), 256, 0, stream>>>(bh, hmw, hmb, nullptr, mu_tok, 8192, 64, 512);
    gemm_nt<0><<<dim3(1, 64), 256, 0, stream>>>(bh, hlw, hlb, nullptr, lv_tok, 8192, 64, 512);

    float* out = (float*)d_out;
    unpatch_k<false><<<NB * 65536 / 256, 256, 0, stream>>>(mu_tok, out);
    unpatch_k<true ><<<NB * 65536 / 256, 256, 0, stream>>>(lv_tok, out + 524288);
    mask_fill_k<<<32, 256, 0, stream>>>(out + 1048576);
    mask_zero_k<<<16, 256, 0, stream>>>(out + 1048576, vis);
}

// Round 4
// 4135.612 us; speedup vs baseline: 2.7023x; 1.1130x over previous
//
#include <hip/hip_runtime.h>
#include <hip/hip_bf16.h>
#include <math.h>

#define NB 8
#define LFULL 1024
#define LVIS 512
#define NREL 3969

typedef __attribute__((ext_vector_type(8))) short s8v;
typedef __attribute__((ext_vector_type(4))) float f4v;

__device__ __forceinline__ float gelu_f(float x) {
    return 0.5f * x * (1.0f + erff(x * 0.7071067811865475f));
}

// fp32 -> bf16 via native conversion (compiler can fuse pairs into v_cvt_pk_bf16_f32)
__device__ __forceinline__ short f2bf(float x) {
    __hip_bfloat16 h = __float2bfloat16(x);
    return __builtin_bit_cast(short, h);
}

// ============ bf16 MFMA GEMM: C = A(M,K) @ W(N,K)^T + bias [+res|+gelu] ======
// MODE: 0 bias, 1 bias+residual, 2 bias+gelu.  M%128==0, N%128==0, K%32==0.
template<int MODE>
__global__ __launch_bounds__(256)
void gemm_bf16(const float* __restrict__ A, const float* __restrict__ W,
               const float* __restrict__ bias, const float* res,
               float* __restrict__ C, int M, int N, int K)
{
    __shared__ __align__(16) short Al[8][64][8];   // [frag][lane][8] fragment-linear
    __shared__ __align__(16) short Wl[8][64][8];
    const int t  = threadIdx.x;
    const int w  = t >> 6, l = t & 63;
    const int lg = l >> 4, lr = l & 15;
    const int bm = blockIdx.y * 128, bn = blockIdx.x * 128;
    const int wm = (w & 1) * 64,  wn = (w >> 1) * 64;

    f4v acc[4][4];
#pragma unroll
    for (int i = 0; i < 4; ++i)
#pragma unroll
        for (int j = 0; j < 4; ++j) acc[i][j] = (f4v){0.f, 0.f, 0.f, 0.f};

    const int srow = t >> 1;            // 0..127
    const int kh   = (t & 1) * 16;      // 0 or 16
    const float* pa = A + (size_t)(bm + srow) * K + kh;
    const float* pw = W + (size_t)(bn + srow) * K + kh;

    for (int k0 = 0; k0 < K; k0 += 32) {
        float4 a0 = *(const float4*)(pa + k0),     a1 = *(const float4*)(pa + k0 + 4);
        float4 a2 = *(const float4*)(pa + k0 + 8), a3 = *(const float4*)(pa + k0 + 12);
        float4 w0 = *(const float4*)(pw + k0),     w1 = *(const float4*)(pw + k0 + 4);
        float4 w2 = *(const float4*)(pw + k0 + 8), w3 = *(const float4*)(pw + k0 + 12);
        __syncthreads();
        {
            s8v p0, p1;
            p0[0]=f2bf(a0.x); p0[1]=f2bf(a0.y); p0[2]=f2bf(a0.z); p0[3]=f2bf(a0.w);
            p0[4]=f2bf(a1.x); p0[5]=f2bf(a1.y); p0[6]=f2bf(a1.z); p0[7]=f2bf(a1.w);
            p1[0]=f2bf(a2.x); p1[1]=f2bf(a2.y); p1[2]=f2bf(a2.z); p1[3]=f2bf(a2.w);
            p1[4]=f2bf(a3.x); p1[5]=f2bf(a3.y); p1[6]=f2bf(a3.z); p1[7]=f2bf(a3.w);
            const int ln0 = (srow & 15) + 16 * (2 * (t & 1) + 0);
            const int ln1 = (srow & 15) + 16 * (2 * (t & 1) + 1);
            *(s8v*)&Al[srow >> 4][ln0][0] = p0;
            *(s8v*)&Al[srow >> 4][ln1][0] = p1;
            p0[0]=f2bf(w0.x); p0[1]=f2bf(w0.y); p0[2]=f2bf(w0.z); p0[3]=f2bf(w0.w);
            p0[4]=f2bf(w1.x); p0[5]=f2bf(w1.y); p0[6]=f2bf(w1.z); p0[7]=f2bf(w1.w);
            p1[0]=f2bf(w2.x); p1[1]=f2bf(w2.y); p1[2]=f2bf(w2.z); p1[3]=f2bf(w2.w);
            p1[4]=f2bf(w3.x); p1[5]=f2bf(w3.y); p1[6]=f2bf(w3.z); p1[7]=f2bf(w3.w);
            *(s8v*)&Wl[srow >> 1 & 7][ln0][0] = p0;   // srow>>4 == (srow>>1&7)? no — keep explicit below
        }
        // NOTE: the W write above must mirror the A write; rewrite correctly:
        __syncthreads();
        s8v af[4], bf[4];
#pragma unroll
        for (int mi = 0; mi < 4; ++mi) af[mi] = *(const s8v*)&Al[(wm >> 4) + mi][l][0];
#pragma unroll
        for (int ni = 0; ni < 4; ++ni) bf[ni] = *(const s8v*)&Wl[(wn >> 4) + ni][l][0];
#pragma unroll
        for (int mi = 0; mi < 4; ++mi)
#pragma unroll
            for (int ni = 0; ni < 4; ++ni)
                acc[mi][ni] = __builtin_amdgcn_mfma_f32_16x16x32_bf16(af[mi], bf[ni], acc[mi][ni], 0, 0, 0);
    }

#pragma unroll
    for (int ni = 0; ni < 4; ++ni) {
        const int col = bn + wn + ni * 16 + lr;
        const float bb = bias[col];
#pragma unroll
        for (int mi = 0; mi < 4; ++mi) {
#pragma unroll
            for (int r = 0; r < 4; ++r) {
                const int rowg = bm + wm + mi * 16 + lg * 4 + r;
                float v = acc[mi][ni][r] + bb;
                if (MODE == 1) v += res[(size_t)rowg * N + col];
                if (MODE == 2) v = gelu_f(v);
                C[(size_t)rowg * N + col] = v;
            }
        }
    }
}

// ---- NOTE: the snippet above had a transcription slip in the W LDS write; the
// real kernel used below is gemm_bf16_fixed (identical structure, correct write).
template<int MODE>
__global__ __launch_bounds__(256)
void gemm_bf16_fixed(const float* __restrict__ A, const float* __restrict__ W,
                     const float* __restrict__ bias, const float* res,
                     float* __restrict__ C, int M, int N, int K)
{
    __shared__ __align__(16) short Al[8][64][8];
    __shared__ __align__(16) short Wl[8][64][8];
    const int t  = threadIdx.x;
    const int w  = t >> 6, l = t & 63;
    const int lg = l >> 4, lr = l & 15;
    const int bm = blockIdx.y * 128, bn = blockIdx.x * 128;
    const int wm = (w & 1) * 64,  wn = (w >> 1) * 64;

    f4v acc[4][4];
#pragma unroll
    for (int i = 0; i < 4; ++i)
#pragma unroll
        for (int j = 0; j < 4; ++j) acc[i][j] = (f4v){0.f, 0.f, 0.f, 0.f};

    const int srow = t >> 1;
    const int kh   = (t & 1) * 16;
    const float* pa = A + (size_t)(bm + srow) * K + kh;
    const float* pw = W + (size_t)(bn + srow) * K + kh;
    const int frag = srow >> 4;
    const int ln0 = (srow & 15) + 16 * (2 * (t & 1) + 0);
    const int ln1 = (srow & 15) + 16 * (2 * (t & 1) + 1);

    for (int k0 = 0; k0 < K; k0 += 32) {
        float4 a0 = *(const float4*)(pa + k0),     a1 = *(const float4*)(pa + k0 + 4);
        float4 a2 = *(const float4*)(pa + k0 + 8), a3 = *(const float4*)(pa + k0 + 12);
        float4 w0 = *(const float4*)(pw + k0),     w1 = *(const float4*)(pw + k0 + 4);
        float4 w2 = *(const float4*)(pw + k0 + 8), w3 = *(const float4*)(pw + k0 + 12);
        __syncthreads();
        {
            s8v p0, p1;
            p0[0]=f2bf(a0.x); p0[1]=f2bf(a0.y); p0[2]=f2bf(a0.z); p0[3]=f2bf(a0.w);
            p0[4]=f2bf(a1.x); p0[5]=f2bf(a1.y); p0[6]=f2bf(a1.z); p0[7]=f2bf(a1.w);
            p1[0]=f2bf(a2.x); p1[1]=f2bf(a2.y); p1[2]=f2bf(a2.z); p1[3]=f2bf(a2.w);
            p1[4]=f2bf(a3.x); p1[5]=f2bf(a3.y); p1[6]=f2bf(a3.z); p1[7]=f2bf(a3.w);
            *(s8v*)&Al[frag][ln0][0] = p0;
            *(s8v*)&Al[frag][ln1][0] = p1;
            p0[0]=f2bf(w0.x); p0[1]=f2bf(w0.y); p0[2]=f2bf(w0.z); p0[3]=f2bf(w0.w);
            p0[4]=f2bf(w1.x); p0[5]=f2bf(w1.y); p0[6]=f2bf(w1.z); p0[7]=f2bf(w1.w);
            p1[0]=f2bf(w2.x); p1[1]=f2bf(w2.y); p1[2]=f2bf(w2.z); p1[3]=f2bf(w2.w);
            p1[4]=f2bf(w3.x); p1[5]=f2bf(w3.y); p1[6]=f2bf(w3.z); p1[7]=f2bf(w3.w);
            *(s8v*)&Wl[frag][ln0][0] = p0;
            *(s8v*)&Wl[frag][ln1][0] = p1;
        }
        __syncthreads();
        s8v af[4], bf[4];
#pragma unroll
        for (int mi = 0; mi < 4; ++mi) af[mi] = *(const s8v*)&Al[(wm >> 4) + mi][l][0];
#pragma unroll
        for (int ni = 0; ni < 4; ++ni) bf[ni] = *(const s8v*)&Wl[(wn >> 4) + ni][l][0];
#pragma unroll
        for (int mi = 0; mi < 4; ++mi)
#pragma unroll
            for (int ni = 0; ni < 4; ++ni)
                acc[mi][ni] = __builtin_amdgcn_mfma_f32_16x16x32_bf16(af[mi], bf[ni], acc[mi][ni], 0, 0, 0);
    }

#pragma unroll
    for (int ni = 0; ni < 4; ++ni) {
        const int col = bn + wn + ni * 16 + lr;
        const float bb = bias[col];
#pragma unroll
        for (int mi = 0; mi < 4; ++mi) {
#pragma unroll
            for (int r = 0; r < 4; ++r) {
                const int rowg = bm + wm + mi * 16 + lg * 4 + r;
                float v = acc[mi][ni][r] + bb;
                if (MODE == 1) v += res[(size_t)rowg * N + col];
                if (MODE == 2) v = gelu_f(v);
                C[(size_t)rowg * N + col] = v;
            }
        }
    }
}

// ---------------- fp32 GEMM (kept for N=64 heads) ---------------------------
template<int MODE>
__global__ __launch_bounds__(256)
void gemm_nt(const float* __restrict__ A, const float* __restrict__ W,
             const float* __restrict__ bias, const float* res,
             float* C, int M, int N, int K)
{
    __shared__ float As[16][128];
    __shared__ float Ws[16][64];
    const int bm = blockIdx.y * 128;
    const int bn = blockIdx.x * 64;
    const int t  = threadIdx.x;
    const int tx = t & 15, ty = t >> 4;
    const int tm = ty * 8, tn = tx * 4;
    const int lr = t >> 2;
    const int lk = (t & 3) << 2;

    float acc[8][4];
#pragma unroll
    for (int i = 0; i < 8; ++i)
#pragma unroll
        for (int j = 0; j < 4; ++j) acc[i][j] = 0.0f;

    const float* pa0 = A + (size_t)(bm + lr) * K + lk;
    const float* pa1 = A + (size_t)(bm + 64 + lr) * K + lk;
    const float* pw  = W + (size_t)(bn + lr) * K + lk;

    for (int k0 = 0; k0 < K; k0 += 16) {
        const float4 a0 = *(const float4*)(pa0 + k0);
        const float4 a1 = *(const float4*)(pa1 + k0);
        const float4 w0 = *(const float4*)(pw  + k0);
        __syncthreads();
        As[lk + 0][lr] = a0.x; As[lk + 1][lr] = a0.y;
        As[lk + 2][lr] = a0.z; As[lk + 3][lr] = a0.w;
        As[lk + 0][64 + lr] = a1.x; As[lk + 1][64 + lr] = a1.y;
        As[lk + 2][64 + lr] = a1.z; As[lk + 3][64 + lr] = a1.w;
        Ws[lk + 0][lr] = w0.x; Ws[lk + 1][lr] = w0.y;
        Ws[lk + 2][lr] = w0.z; Ws[lk + 3][lr] = w0.w;
        __syncthreads();
#pragma unroll
        for (int k = 0; k < 16; ++k) {
            const float4 av0 = *(const float4*)&As[k][tm];
            const float4 av1 = *(const float4*)&As[k][tm + 4];
            const float4 wv  = *(const float4*)&Ws[k][tn];
            const float am[8] = {av0.x, av0.y, av0.z, av0.w, av1.x, av1.y, av1.z, av1.w};
            const float wn4[4] = {wv.x, wv.y, wv.z, wv.w};
#pragma unroll
            for (int i = 0; i < 8; ++i)
#pragma unroll
                for (int j = 0; j < 4; ++j) acc[i][j] += am[i] * wn4[j];
        }
    }

    const float b0 = bias[bn + tn + 0], b1 = bias[bn + tn + 1];
    const float b2 = bias[bn + tn + 2], b3 = bias[bn + tn + 3];
#pragma unroll
    for (int i = 0; i < 8; ++i) {
        const size_t row = (size_t)(bm + tm + i);
        float4 v = make_float4(acc[i][0] + b0, acc[i][1] + b1,
                               acc[i][2] + b2, acc[i][3] + b3);
        if (MODE == 1) {
            const float4 r4 = *(const float4*)(res + row * N + bn + tn);
            v.x += r4.x; v.y += r4.y; v.z += r4.z; v.w += r4.w;
        }
        if (MODE == 2) {
            v.x = gelu_f(v.x); v.y = gelu_f(v.y);
            v.z = gelu_f(v.z); v.w = gelu_f(v.w);
        }
        *(float4*)(C + row * N + bn + tn) = v;
    }
}

// ============ MFMA flash attention v2: swapped QK^T, lane-local softmax ======
// qkv: (B,Lx,3*Cx), f = s*Cx + h*64 + d.  btt: [H][NREL] transposed bias table.
// grid (Lx/64, H, B), 256 thr = 4 waves; wave w owns q rows [q0+16w, 16).
// K-tile = 64 keys.
template<bool HAS_IDX>
__global__ __launch_bounds__(256)
void attn_v2(const float* __restrict__ qkv, const float* __restrict__ btt,
             const int* vis, float* __restrict__ out, int Lx, int Cx)
{
    __shared__ __align__(16) short Kl[64][72];      // [key][d]
    __shared__ __align__(16) short Vl[64][72];      // [d][key]
    __shared__ __align__(16) short Pl[4][16][72];   // per-wave [q][key]
    __shared__ int qpos[64];
    __shared__ int kpos[64];

    const int q0 = blockIdx.x * 64;
    const int h  = blockIdx.y, bb = blockIdx.z;
    const int t  = threadIdx.x;
    const int w  = t >> 6, l = t & 63;
    const int lg = l >> 4, lr = l & 15;
    const int C3 = 3 * Cx;
    const float* bth = btt + (size_t)h * NREL;

    // Q fragment (B-operand of swapped MFMA): lane holds Q[q=lr][d=lg*8+e]
    s8v qa[2];
    {
        const float* src = qkv + (size_t)(bb * Lx + q0 + w * 16 + lr) * C3 + h * 64 + lg * 8;
#pragma unroll
        for (int c = 0; c < 2; ++c) {
            float4 x0 = *(const float4*)(src + c * 32);
            float4 x1 = *(const float4*)(src + c * 32 + 4);
            s8v v;
            v[0]=f2bf(x0.x); v[1]=f2bf(x0.y); v[2]=f2bf(x0.z); v[3]=f2bf(x0.w);
            v[4]=f2bf(x1.x); v[5]=f2bf(x1.y); v[6]=f2bf(x1.z); v[7]=f2bf(x1.w);
            qa[c] = v;
        }
    }
    int qi, qj;
    if (HAS_IDX) {
        if (t < 64) qpos[t] = vis[q0 + t];
        __syncthreads();
        const int qv = qpos[w * 16 + lr];
        qi = qv >> 5; qj = qv & 31;
    } else {
        const int qv = q0 + w * 16 + lr;
        qi = qv >> 5; qj = qv & 31;
    }

    float m_run = -INFINITY, l_run = 0.0f;
    f4v o[4];
#pragma unroll
    for (int df = 0; df < 4; ++df) o[df] = (f4v){0.f, 0.f, 0.f, 0.f};

    const int nt = Lx >> 6;
    for (int kt = 0; kt < nt; ++kt) {
        __syncthreads();
        {   // stage K: [key][d]  (thread: key=t>>2, dh=(t&3)*16)
            const int key = t >> 2, dh = (t & 3) * 16;
            const float* src = qkv + (size_t)(bb * Lx + kt * 64 + key) * C3 + Cx + h * 64 + dh;
            float4 x0 = *(const float4*)(src),     x1 = *(const float4*)(src + 4);
            float4 x2 = *(const float4*)(src + 8), x3 = *(const float4*)(src + 12);
            s8v v0, v1;
            v0[0]=f2bf(x0.x); v0[1]=f2bf(x0.y); v0[2]=f2bf(x0.z); v0[3]=f2bf(x0.w);
            v0[4]=f2bf(x1.x); v0[5]=f2bf(x1.y); v0[6]=f2bf(x1.z); v0[7]=f2bf(x1.w);
            v1[0]=f2bf(x2.x); v1[1]=f2bf(x2.y); v1[2]=f2bf(x2.z); v1[3]=f2bf(x2.w);
            v1[4]=f2bf(x3.x); v1[5]=f2bf(x3.y); v1[6]=f2bf(x3.z); v1[7]=f2bf(x3.w);
            *(s8v*)&Kl[key][dh]     = v0;
            *(s8v*)&Kl[key][dh + 8] = v1;
        }
        {   // stage V transposed: [d][key]  (thread: key=t&63, dh=(t>>6)*16)
            const int key = t & 63, dh = (t >> 6) * 16;
            const float* src = qkv + (size_t)(bb * Lx + kt * 64 + key) * C3 + 2 * Cx + h * 64 + dh;
            float4 x0 = *(const float4*)(src),     x1 = *(const float4*)(src + 4);
            float4 x2 = *(const float4*)(src + 8), x3 = *(const float4*)(src + 12);
            Vl[dh + 0][key] = f2bf(x0.x);  Vl[dh + 1][key] = f2bf(x0.y);
            Vl[dh + 2][key] = f2bf(x0.z);  Vl[dh + 3][key] = f2bf(x0.w);
            Vl[dh + 4][key] = f2bf(x1.x);  Vl[dh + 5][key] = f2bf(x1.y);
            Vl[dh + 6][key] = f2bf(x1.z);  Vl[dh + 7][key] = f2bf(x1.w);
            Vl[dh + 8][key] = f2bf(x2.x);  Vl[dh + 9][key] = f2bf(x2.y);
            Vl[dh +10][key] = f2bf(x2.z);  Vl[dh +11][key] = f2bf(x2.w);
            Vl[dh +12][key] = f2bf(x3.x);  Vl[dh +13][key] = f2bf(x3.y);
            Vl[dh +14][key] = f2bf(x3.z);  Vl[dh +15][key] = f2bf(x3.w);
        }
        if (HAS_IDX && t < 64) kpos[t] = vis[kt * 64 + t];
        __syncthreads();

        // S^T[key][q] via mfma(K, Q): frag f covers keys f*16 + lg*4 + r, col q = lr
        f4v st[4];
#pragma unroll
        for (int f = 0; f < 4; ++f) {
            st[f] = (f4v){0.f, 0.f, 0.f, 0.f};
#pragma unroll
            for (int c = 0; c < 2; ++c) {
                s8v ka = *(const s8v*)&Kl[f * 16 + lr][c * 32 + lg * 8];
                st[f] = __builtin_amdgcn_mfma_f32_16x16x32_bf16(ka, qa[c], st[f], 0, 0, 0);
            }
        }

        // scale + bias: lane owns q = lr, 16 keys
        float sv[16];
        if (HAS_IDX) {
#pragma unroll
            for (int f = 0; f < 4; ++f)
#pragma unroll
                for (int r = 0; r < 4; ++r) {
                    const int kv = kpos[f * 16 + lg * 4 + r];
                    const int rel = (qi - (kv >> 5) + 31) * 63 + (qj - (kv & 31) + 31);
                    sv[f * 4 + r] = st[f][r] * 0.125f + bth[rel];
                }
        } else {
#pragma unroll
            for (int f = 0; f < 4; ++f) {
                const int kbase = kt * 64 + f * 16 + lg * 4;
                const int R0 = (qi - (kbase >> 5) + 31) * 63 + (qj - (kbase & 31) + 31);
#pragma unroll
                for (int r = 0; r < 4; ++r)
                    sv[f * 4 + r] = st[f][r] * 0.125f + bth[R0 - r];
            }
        }

        // lane-local softmax: 16 regs + reduce across lanes l^16, l^32 (same lr)
        float mx = sv[0];
#pragma unroll
        for (int i = 1; i < 16; ++i) mx = fmaxf(mx, sv[i]);
        mx = fmaxf(mx, __shfl_xor(mx, 16));
        mx = fmaxf(mx, __shfl_xor(mx, 32));
        const float mnew = fmaxf(m_run, mx);
        const float alpha = __expf(m_run - mnew);
        float rs = 0.0f;
#pragma unroll
        for (int i = 0; i < 16; ++i) { sv[i] = __expf(sv[i] - mnew); rs += sv[i]; }
        rs += __shfl_xor(rs, 16);
        rs += __shfl_xor(rs, 32);
        l_run = l_run * alpha + rs;
        m_run = mnew;

        // write P in [q][key] layout (row = lr, 4-key groups contiguous)
#pragma unroll
        for (int f = 0; f < 4; ++f) {
            short4 p4;
            p4.x = f2bf(sv[f * 4 + 0]); p4.y = f2bf(sv[f * 4 + 1]);
            p4.z = f2bf(sv[f * 4 + 2]); p4.w = f2bf(sv[f * 4 + 3]);
            *(short4*)&Pl[w][lr][f * 16 + lg * 4] = p4;
        }

        // rescale O (row = lg*4+r): fetch that row's alpha from lane lg*4+r
        float al[4];
#pragma unroll
        for (int r = 0; r < 4; ++r) al[r] = __shfl(alpha, lg * 4 + r);
#pragma unroll
        for (int df = 0; df < 4; ++df) {
            o[df][0] *= al[0]; o[df][1] *= al[1];
            o[df][2] *= al[2]; o[df][3] *= al[3];
        }
        __syncthreads();

        // O += P V : A = P[q][k], B = V[k][d] (from Vl [d][key])
#pragma unroll
        for (int c = 0; c < 2; ++c) {
            s8v pa = *(const s8v*)&Pl[w][lr][c * 32 + lg * 8];
#pragma unroll
            for (int df = 0; df < 4; ++df) {
                s8v vb = *(const s8v*)&Vl[df * 16 + lr][c * 32 + lg * 8];
                o[df] = __builtin_amdgcn_mfma_f32_16x16x32_bf16(pa, vb, o[df], 0, 0, 0);
            }
        }
    }

    float il[4];
#pragma unroll
    for (int r = 0; r < 4; ++r) il[r] = 1.0f / __shfl(l_run, lg * 4 + r);
#pragma unroll
    for (int df = 0; df < 4; ++df)
#pragma unroll
        for (int r = 0; r < 4; ++r)
            out[(size_t)(bb * Lx + q0 + w * 16 + lg * 4 + r) * Cx + h * 64 + df * 16 + lr] =
                o[df][r] * il[r];
}

// ---------------- bias table transpose: [D][NREL][H] -> [D][H][NREL] ---------
__global__ void transpose_bt_k(const float* __restrict__ bt, float* __restrict__ dst,
                               int H, int n)
{
    const int id = blockIdx.x * 256 + threadIdx.x;
    if (id >= n) return;
    const int rel = id % NREL;
    const int dh  = id / NREL;
    const int h   = dh % H;
    const int d   = dh / H;
    dst[id] = bt[((size_t)d * NREL + rel) * H + h];
}

// ---------------- LayerNorm (one block per row) ------------------------------
__global__ __launch_bounds__(256)
void ln_k(const float* __restrict__ x, const float* __restrict__ g,
          const float* __restrict__ be, float* __restrict__ y, int C)
{
    const int row = blockIdx.x;
    const float* xr = x + (size_t)row * C;
    float s = 0.f, ss = 0.f;
    for (int c = threadIdx.x; c < C; c += 256) { const float v = xr[c]; s += v; ss += v * v; }
#pragma unroll
    for (int off = 1; off < 64; off <<= 1) { s += __shfl_xor(s, off); ss += __shfl_xor(ss, off); }
    __shared__ float rs[4], rss[4];
    const int w = threadIdx.x >> 6;
    if ((threadIdx.x & 63) == 0) { rs[w] = s; rss[w] = ss; }
    __syncthreads();
    s  = rs[0] + rs[1] + rs[2] + rs[3];
    ss = rss[0] + rss[1] + rss[2] + rss[3];
    const float mean = s / C;
    const float rstd = rsqrtf(ss / C - mean * mean + 1e-5f);
    float* yr = y + (size_t)row * C;
    for (int c = threadIdx.x; c < C; c += 256)
        yr[c] = (xr[c] - mean) * rstd * g[c] + be[c];
}

// ---------------- glue kernels ----------------------------------------------
__global__ void gather_tokens_k(const float* __restrict__ x, const int* __restrict__ vis,
                                float* __restrict__ tok)
{
    const int id = blockIdx.x * 256 + threadIdx.x;
    const int ti = id & 127;
    const int j  = (id >> 7) & 511;
    const int b  = id >> 16;
    const int ll = vis[j];
    const int hp = ll >> 5, wp = ll & 31;
    const int pi = ti >> 4, pj = (ti >> 1) & 7, ch = ti & 1;
    tok[id] = x[(((size_t)(b * 2 + ch) * 256) + hp * 8 + pi) * 256 + wp * 8 + pj];
}

__global__ void add_pos_vis_k(float* __restrict__ y, const float* __restrict__ pos,
                              const int* __restrict__ vis)
{
    const int id = blockIdx.x * 256 + threadIdx.x;
    const int c = id % 768;
    const int j = (id / 768) & 511;
    y[id] += pos[(size_t)vis[j] * 768 + c];
}

__global__ void fill_dec_k(float* __restrict__ y, const float* __restrict__ mtok,
                           const float* __restrict__ pos)
{
    const int id = blockIdx.x * 256 + threadIdx.x;
    const int c = id & 511;
    const int ll = (id >> 9) & 1023;
    y[id] = mtok[c] + pos[(ll << 9) + c];
}

__global__ void scatter_vis_k(float* __restrict__ y, const float* __restrict__ dvis,
                              const float* __restrict__ pos, const int* __restrict__ vis)
{
    const int id = blockIdx.x * 256 + threadIdx.x;
    const int c = id & 511;
    const int j = (id >> 9) & 511;
    const int b = id >> 18;
    const int ll = vis[j];
    y[(((size_t)b * 1024 + ll) << 9) + c] = dvis[id] + pos[(ll << 9) + c];
}

template<bool CLIP>
__global__ void unpatch_k(const float* __restrict__ tk, float* __restrict__ out)
{
    const int id = blockIdx.x * 256 + threadIdx.x;
    const int j = id & 255, i = (id >> 8) & 255, b = id >> 16;
    const int hp = i >> 3, pi = i & 7, wp = j >> 3, pj = j & 7;
    float v = tk[((size_t)b * 1024 + hp * 32 + wp) * 64 + pi * 8 + pj];
    if (CLIP) v = fminf(6.0f, fmaxf(-6.0f, v));
    out[id] = v;
}

__global__ void mask_fill_k(float* m) { m[blockIdx.x * 256 + threadIdx.x] = 1.0f; }

__global__ void mask_zero_k(float* m, const int* __restrict__ vis)
{
    const int id = blockIdx.x * 256 + threadIdx.x;
    const int b = id >> 9, j = id & 511;
    m[b * 1024 + vis[j]] = 0.0f;
}

// ---------------- launcher ---------------------------------------------------
extern "C" void kernel_launch(void* const* d_in, const int* in_sizes, int n_in,
                              void* d_out, int out_size, void* d_ws, size_t ws_size,
                              hipStream_t stream)
{
    const float* x       = (const float*)d_in[0];
    const int*   vis     = (const int*  )d_in[1];
    const float* eew     = (const float*)d_in[2];
    const float* eeb     = (const float*)d_in[3];
    const float* pos_enc = (const float*)d_in[4];
    const float* e_ln1s  = (const float*)d_in[5];
    const float* e_ln1b  = (const float*)d_in[6];
    const float* e_qkvw  = (const float*)d_in[7];
    const float* e_qkvb  = (const float*)d_in[8];
    const float* e_bt    = (const float*)d_in[9];
    const float* e_pw    = (const float*)d_in[10];
    const float* e_pb    = (const float*)d_in[11];
    const float* e_ln2s  = (const float*)d_in[12];
    const float* e_ln2b  = (const float*)d_in[13];
    const float* e_f1w   = (const float*)d_in[14];
    const float* e_f1b   = (const float*)d_in[15];
    const float* e_f2w   = (const float*)d_in[16];
    const float* e_f2b   = (const float*)d_in[17];
    const float* d_ln1s  = (const float*)d_in[18];
    const float* d_ln1b  = (const float*)d_in[19];
    const float* d_qkvw  = (const float*)d_in[20];
    const float* d_qkvb  = (const float*)d_in[21];
    const float* d_bt    = (const float*)d_in[22];
    const float* d_pw    = (const float*)d_in[23];
    const float* d_pb    = (const float*)d_in[24];
    const float* d_ln2s  = (const float*)d_in[25];
    const float* d_ln2b  = (const float*)d_in[26];
    const float* d_f1w   = (const float*)d_in[27];
    const float* d_f1b   = (const float*)d_in[28];
    const float* d_f2w   = (const float*)d_in[29];
    const float* d_f2b   = (const float*)d_in[30];
    const float* en_s    = (const float*)d_in[31];
    const float* en_b    = (const float*)d_in[32];
    const float* dew     = (const float*)d_in[33];
    const float* deb     = (const float*)d_in[34];
    const float* mtok    = (const float*)d_in[35];
    const float* pos_dec = (const float*)d_in[36];
    const float* dn_s    = (const float*)d_in[37];
    const float* dn_b    = (const float*)d_in[38];
    const float* hmw     = (const float*)d_in[39];
    const float* hmb     = (const float*)d_in[40];
    const float* hlw     = (const float*)d_in[41];
    const float* hlb     = (const float*)d_in[42];
    (void)in_sizes; (void)n_in; (void)out_size; (void)ws_size;

    float* ws   = (float*)d_ws;
    float* bx    = ws;                  // activations (residual stream)
    float* bh    = ws + 4194304;        // LN output
    float* batt  = ws + 8388608;        // attn out / dec_vis
    float* bbig  = ws + 12582912;       // qkv / mlp hidden / tokens / head out
    float* btt_e = ws + 29360128;       // 6*12*NREL = 285768 floats
    float* btt_d = btt_e + 6 * 12 * NREL;  // 4*8*NREL = 127008 floats

    // ---- bias table transposes (once per launch, tiny) ----
    transpose_bt_k<<<(6 * 12 * NREL + 255) / 256, 256, 0, stream>>>(e_bt, btt_e, 12, 6 * 12 * NREL);
    transpose_bt_k<<<(4 * 8 * NREL + 255) / 256, 256, 0, stream>>>(d_bt, btt_d, 8, 4 * 8 * NREL);

    // ---- patchify(visible) + encoder embed + pos ----
    gather_tokens_k<<<NB * LVIS * 128 / 256, 256, 0, stream>>>(x, vis, bbig);
    gemm_bf16_fixed<0><<<dim3(6, 32), 256, 0, stream>>>(bbig, eew, eeb, nullptr, bx, 4096, 768, 128);
    add_pos_vis_k<<<NB * LVIS * 768 / 256, 256, 0, stream>>>(bx, pos_enc, vis);

    // ---- encoder blocks ----
    for (int d = 0; d < 6; ++d) {
        ln_k<<<4096, 256, 0, stream>>>(bx, e_ln1s + d * 768, e_ln1b + d * 768, bh, 768);
        gemm_bf16_fixed<0><<<dim3(18, 32), 256, 0, stream>>>(bh, e_qkvw + (size_t)d * 2304 * 768,
                                                             e_qkvb + d * 2304, nullptr, bbig, 4096, 2304, 768);
        attn_v2<true><<<dim3(8, 12, NB), 256, 0, stream>>>(bbig, btt_e + (size_t)d * 12 * NREL,
                                                           vis, batt, 512, 768);
        gemm_bf16_fixed<1><<<dim3(6, 32), 256, 0, stream>>>(batt, e_pw + (size_t)d * 768 * 768,
                                                            e_pb + d * 768, bx, bx, 4096, 768, 768);
        ln_k<<<4096, 256, 0, stream>>>(bx, e_ln2s + d * 768, e_ln2b + d * 768, bh, 768);
        gemm_bf16_fixed<2><<<dim3(24, 32), 256, 0, stream>>>(bh, e_f1w + (size_t)d * 3072 * 768,
                                                             e_f1b + d * 3072, nullptr, bbig, 4096, 3072, 768);
        gemm_bf16_fixed<1><<<dim3(6, 32), 256, 0, stream>>>(bbig, e_f2w + (size_t)d * 768 * 3072,
                                                            e_f2b + d * 768, bx, bx, 4096, 768, 3072);
    }

    // ---- encoder norm + decoder embed + sequence build ----
    ln_k<<<4096, 256, 0, stream>>>(bx, en_s, en_b, bh, 768);
    gemm_bf16_fixed<0><<<dim3(4, 32), 256, 0, stream>>>(bh, dew, deb, nullptr, batt, 4096, 512, 768);
    fill_dec_k<<<NB * LFULL * 512 / 256, 256, 0, stream>>>(bx, mtok, pos_dec);
    scatter_vis_k<<<NB * LVIS * 512 / 256, 256, 0, stream>>>(bx, batt, pos_dec, vis);

    // ---- decoder blocks ----
    for (int d = 0; d < 4; ++d) {
        ln_k<<<8192, 256, 0, stream>>>(bx, d_ln1s + d * 512, d_ln1b + d * 512, bh, 512);
        gemm_bf16_fixed<0><<<dim3(12, 64), 256, 0, stream>>>(bh, d_qkvw + (size_t)d * 1536 * 512,
                                                             d_qkvb + d * 1536, nullptr, bbig, 8192, 1536, 512);
        attn_v2<false><<<dim3(16, 8, NB), 256, 0, stream>>>(bbig, btt_d + (size_t)d * 8 * NREL,
                                                            nullptr, batt, 1024, 512);
        gemm_bf16_fixed<1><<<dim3(4, 64), 256, 0, stream>>>(batt, d_pw + (size_t)d * 512 * 512,
                                                            d_pb + d * 512, bx, bx, 8192, 512, 512);
        ln_k<<<8192, 256, 0, stream>>>(bx, d_ln2s + d * 512, d_ln2b + d * 512, bh, 512);
        gemm_bf16_fixed<2><<<dim3(16, 64), 256, 0, stream>>>(bh, d_f1w + (size_t)d * 2048 * 512,
                                                             d_f1b + d * 2048, nullptr, bbig, 8192, 2048, 512);
        gemm_bf16_fixed<1><<<dim3(4, 64), 256, 0, stream>>>(bbig, d_f2w + (size_t)d * 512 * 2048,
                                                            d_f2b + d * 512, bx, bx, 8192, 512, 2048);
    }

    // ---- final norm + heads + unpatchify + mask ----
    ln_k<<<8192, 256, 0, stream>>>(bx, dn_s, dn_b, bh, 512);
    float* mu_tok = bbig;
    float* lv_tok = bbig + 524288;
    gemm_nt<0><<<dim3(1, 64), 256, 0, stream>>>(bh, hmw, hmb, nullptr, mu_tok, 8192, 64, 512);
    gemm_nt<0><<<dim3(1, 64), 256, 0, stream>>>(bh, hlw, hlb, nullptr, lv_tok, 8192, 64, 512);

    float* out = (float*)d_out;
    unpatch_k<false><<<NB * 65536 / 256, 256, 0, stream>>>(mu_tok, out);
    unpatch_k<true ><<<NB * 65536 / 256, 256, 0, stream>>>(lv_tok, out + 524288);
    mask_fill_k<<<32, 256, 0, stream>>>(out + 1048576);
    mask_zero_k<<<16, 256, 0, stream>>>(out + 1048576, vis);
}

// Round 6
// 3432.469 us; speedup vs baseline: 3.2559x; 1.2049x over previous
//
#include <hip/hip_runtime.h>
#include <hip/hip_bf16.h>
#include <math.h>

#define NB 8
#define LFULL 1024
#define LVIS 512
#define NREL 3969

typedef __attribute__((ext_vector_type(8))) short s8v;
typedef __attribute__((ext_vector_type(4))) float f4v;

__device__ __forceinline__ float gelu_f(float x) {
    return 0.5f * x * (1.0f + erff(x * 0.7071067811865475f));
}
__device__ __forceinline__ short f2bf(float x) {
    __hip_bfloat16 h = __float2bfloat16(x);
    return __builtin_bit_cast(short, h);
}
__device__ __forceinline__ float bf2f(short s) {
    unsigned u = ((unsigned)(unsigned short)s) << 16;
    return __builtin_bit_cast(float, u);
}

// ============ GEMM: C = A(M,K)bf16 @ W(N,K)^T fp32 + bias [+res|+gelu] =======
// MODE: 0 bias, 1 bias+residual(fp32), 2 bias+gelu. OUTBF: write bf16.
// SPLITK: gridDim.z splits of K, raw partial atomically added to fp32 C.
// 256 thr = 4 waves; tile 128x128; BK=64; register prefetch of next K-tile.
template<int MODE, bool OUTBF, bool SPLITK>
__global__ __launch_bounds__(256)
void gemm_a16(const short* __restrict__ A, const float* __restrict__ W,
              const float* __restrict__ bias, const float* res,
              void* __restrict__ Cv, int M, int N, int K)
{
    __shared__ __align__(16) short Al[16][64][8];   // [m*2+kc][lane][8]
    __shared__ __align__(16) short Wl[16][64][8];
    const int t  = threadIdx.x;
    const int w  = t >> 6, l = t & 63;
    const int lg = l >> 4, lr = l & 15;
    const int bm = blockIdx.y * 128, bn = blockIdx.x * 128;
    const int wm = (w & 1) * 64,  wn = (w >> 1) * 64;

    const int Kc    = K / gridDim.z;
    const int kbase = blockIdx.z * Kc;

    f4v acc[4][4];
#pragma unroll
    for (int i = 0; i < 4; ++i)
#pragma unroll
        for (int j = 0; j < 4; ++j) acc[i][j] = (f4v){0.f, 0.f, 0.f, 0.f};

    const int srow = t >> 1;         // 0..127
    const int kc_  = t & 1;          // which 32-k half of the 64-k step
    const int slot = (srow >> 4) * 2 + kc_;
    const int lnb  = srow & 15;
    const short* pa = A + (size_t)(bm + srow) * K + kbase + kc_ * 32;
    const float* pw = W + (size_t)(bn + srow) * K + kbase + kc_ * 32;

    const int nk = Kc >> 6;
    s8v   ra[4];
    float4 rw[8];
#pragma unroll
    for (int j = 0; j < 4; ++j) ra[j] = *(const s8v*)(pa + j * 8);
#pragma unroll
    for (int j = 0; j < 8; ++j) rw[j] = *(const float4*)(pw + j * 4);

    for (int it = 0; it < nk; ++it) {
        // convert W regs -> bf16 (waits on vmcnt internally)
        s8v wb[4];
#pragma unroll
        for (int j = 0; j < 4; ++j) {
            const float4 u = rw[2 * j], v = rw[2 * j + 1];
            s8v p;
            p[0]=f2bf(u.x); p[1]=f2bf(u.y); p[2]=f2bf(u.z); p[3]=f2bf(u.w);
            p[4]=f2bf(v.x); p[5]=f2bf(v.y); p[6]=f2bf(v.z); p[7]=f2bf(v.w);
            wb[j] = p;
        }
        __syncthreads();
#pragma unroll
        for (int j = 0; j < 4; ++j) {
            *(s8v*)&Al[slot][lnb + 16 * j][0] = ra[j];
            *(s8v*)&Wl[slot][lnb + 16 * j][0] = wb[j];
        }
        __syncthreads();
        if (it + 1 < nk) {   // issue next tile's loads early; latency hides under MFMA
            const int k0 = (it + 1) << 6;
#pragma unroll
            for (int j = 0; j < 4; ++j) ra[j] = *(const s8v*)(pa + k0 + j * 8);
#pragma unroll
            for (int j = 0; j < 8; ++j) rw[j] = *(const float4*)(pw + k0 + j * 4);
        }
#pragma unroll
        for (int kc = 0; kc < 2; ++kc) {
            s8v af[4], bf[4];
#pragma unroll
            for (int mi = 0; mi < 4; ++mi) af[mi] = *(const s8v*)&Al[((wm >> 4) + mi) * 2 + kc][l][0];
#pragma unroll
            for (int ni = 0; ni < 4; ++ni) bf[ni] = *(const s8v*)&Wl[((wn >> 4) + ni) * 2 + kc][l][0];
#pragma unroll
            for (int mi = 0; mi < 4; ++mi)
#pragma unroll
                for (int ni = 0; ni < 4; ++ni)
                    acc[mi][ni] = __builtin_amdgcn_mfma_f32_16x16x32_bf16(af[mi], bf[ni], acc[mi][ni], 0, 0, 0);
        }
    }

    if constexpr (SPLITK) {
        float* C = (float*)Cv;
#pragma unroll
        for (int ni = 0; ni < 4; ++ni) {
            const int col = bn + wn + ni * 16 + lr;
#pragma unroll
            for (int mi = 0; mi < 4; ++mi)
#pragma unroll
                for (int r = 0; r < 4; ++r) {
                    const int rowg = bm + wm + mi * 16 + lg * 4 + r;
                    atomicAdd(&C[(size_t)rowg * N + col], acc[mi][ni][r]);
                }
        }
    } else {
#pragma unroll
        for (int ni = 0; ni < 4; ++ni) {
            const int col = bn + wn + ni * 16 + lr;
            const float bb = bias[col];
#pragma unroll
            for (int mi = 0; mi < 4; ++mi)
#pragma unroll
                for (int r = 0; r < 4; ++r) {
                    const int rowg = bm + wm + mi * 16 + lg * 4 + r;
                    float v = acc[mi][ni][r] + bb;
                    if (MODE == 1) v += res[(size_t)rowg * N + col];
                    if (MODE == 2) v = gelu_f(v);
                    if constexpr (OUTBF) ((short*)Cv)[(size_t)rowg * N + col] = f2bf(v);
                    else                 ((float*)Cv)[(size_t)rowg * N + col] = v;
                }
        }
    }
}

// ---------------- prefill: y += bias (in-place, before split-K atomics) ------
__global__ void prefill_k(float* __restrict__ y, const float* __restrict__ bias,
                          int N, int n)
{
    const int id = blockIdx.x * 256 + threadIdx.x;
    if (id >= n) return;
    const int col = id - (id / N) * N;
    y[id] += bias[col];
}

// ============ MFMA flash attention: swapped QK^T, lane-local softmax =========
// qkv bf16: (B,Lx,3*Cx), f = s*Cx + h*64 + d.  btt: [H][NREL] fp32.
// grid (Lx/64, H, B), 256 thr = 4 waves; wave w owns q rows [q0+16w,16).
// K-tile = 64 keys.
template<bool HAS_IDX>
__global__ __launch_bounds__(256)
void attn_v2(const short* __restrict__ qkv, const float* __restrict__ btt,
             const int* vis, short* __restrict__ out, int Lx, int Cx)
{
    __shared__ __align__(16) short Kl[64][72];      // [key][d]
    __shared__ __align__(16) short Vl[64][72];      // [d][key]
    __shared__ __align__(16) short Pl[4][16][72];   // per-wave [q][key]
    __shared__ int qpos[64];
    __shared__ int kpos[64];

    const int q0 = blockIdx.x * 64;
    const int h  = blockIdx.y, bb = blockIdx.z;
    const int t  = threadIdx.x;
    const int w  = t >> 6, l = t & 63;
    const int lg = l >> 4, lr = l & 15;
    const int C3 = 3 * Cx;
    const float* bth = btt + (size_t)h * NREL;

    // Q fragment: lane holds Q[q=lr][d=lg*8+e], 2 d-chunks (direct bf16 load)
    s8v qa[2];
    {
        const short* src = qkv + (size_t)(bb * Lx + q0 + w * 16 + lr) * C3 + h * 64 + lg * 8;
        qa[0] = *(const s8v*)(src);
        qa[1] = *(const s8v*)(src + 32);
    }
    int qi, qj;
    if (HAS_IDX) {
        if (t < 64) qpos[t] = vis[q0 + t];
        __syncthreads();
        const int qv = qpos[w * 16 + lr];
        qi = qv >> 5; qj = qv & 31;
    } else {
        const int qv = q0 + w * 16 + lr;
        qi = qv >> 5; qj = qv & 31;
    }

    float m_run = -INFINITY, l_run = 0.0f;
    f4v o[4];
#pragma unroll
    for (int df = 0; df < 4; ++df) o[df] = (f4v){0.f, 0.f, 0.f, 0.f};

    const int nt = Lx >> 6;
    for (int kt = 0; kt < nt; ++kt) {
        __syncthreads();
        {   // stage K: [key][d]  (thread: key=t>>2, dh=(t&3)*16)
            const int key = t >> 2, dh = (t & 3) * 16;
            const short* src = qkv + (size_t)(bb * Lx + kt * 64 + key) * C3 + Cx + h * 64 + dh;
            *(s8v*)&Kl[key][dh]     = *(const s8v*)(src);
            *(s8v*)&Kl[key][dh + 8] = *(const s8v*)(src + 8);
        }
        {   // stage V transposed: [d][key]  (thread: key=t&63, dh=(t>>6)*16)
            const int key = t & 63, dh = (t >> 6) * 16;
            const short* src = qkv + (size_t)(bb * Lx + kt * 64 + key) * C3 + 2 * Cx + h * 64 + dh;
            const s8v v0 = *(const s8v*)(src);
            const s8v v1 = *(const s8v*)(src + 8);
#pragma unroll
            for (int e = 0; e < 8; ++e) Vl[dh + e][key] = v0[e];
#pragma unroll
            for (int e = 0; e < 8; ++e) Vl[dh + 8 + e][key] = v1[e];
        }
        if (HAS_IDX && t < 64) kpos[t] = vis[kt * 64 + t];
        __syncthreads();

        // S^T[key][q] via mfma(K, Q): frag f covers keys f*16+lg*4+r, col q=lr
        f4v st[4];
#pragma unroll
        for (int f = 0; f < 4; ++f) {
            st[f] = (f4v){0.f, 0.f, 0.f, 0.f};
#pragma unroll
            for (int c = 0; c < 2; ++c) {
                s8v ka = *(const s8v*)&Kl[f * 16 + lr][c * 32 + lg * 8];
                st[f] = __builtin_amdgcn_mfma_f32_16x16x32_bf16(ka, qa[c], st[f], 0, 0, 0);
            }
        }

        // scale + bias: lane owns q = lr, 16 keys
        float sv[16];
        if (HAS_IDX) {
#pragma unroll
            for (int f = 0; f < 4; ++f)
#pragma unroll
                for (int r = 0; r < 4; ++r) {
                    const int kv = kpos[f * 16 + lg * 4 + r];
                    const int rel = (qi - (kv >> 5) + 31) * 63 + (qj - (kv & 31) + 31);
                    sv[f * 4 + r] = st[f][r] * 0.125f + bth[rel];
                }
        } else {
#pragma unroll
            for (int f = 0; f < 4; ++f) {
                const int kbase = kt * 64 + f * 16 + lg * 4;
                const int R0 = (qi - (kbase >> 5) + 31) * 63 + (qj - (kbase & 31) + 31);
#pragma unroll
                for (int r = 0; r < 4; ++r)
                    sv[f * 4 + r] = st[f][r] * 0.125f + bth[R0 - r];
            }
        }

        // lane-local softmax: 16 regs + reduce across lanes l^16, l^32
        float mx = sv[0];
#pragma unroll
        for (int i = 1; i < 16; ++i) mx = fmaxf(mx, sv[i]);
        mx = fmaxf(mx, __shfl_xor(mx, 16));
        mx = fmaxf(mx, __shfl_xor(mx, 32));
        const float mnew = fmaxf(m_run, mx);
        const float alpha = __expf(m_run - mnew);
        float rs = 0.0f;
#pragma unroll
        for (int i = 0; i < 16; ++i) { sv[i] = __expf(sv[i] - mnew); rs += sv[i]; }
        rs += __shfl_xor(rs, 16);
        rs += __shfl_xor(rs, 32);
        l_run = l_run * alpha + rs;
        m_run = mnew;

#pragma unroll
        for (int f = 0; f < 4; ++f) {
            short4 p4;
            p4.x = f2bf(sv[f * 4 + 0]); p4.y = f2bf(sv[f * 4 + 1]);
            p4.z = f2bf(sv[f * 4 + 2]); p4.w = f2bf(sv[f * 4 + 3]);
            *(short4*)&Pl[w][lr][f * 16 + lg * 4] = p4;
        }

        float al[4];
#pragma unroll
        for (int r = 0; r < 4; ++r) al[r] = __shfl(alpha, lg * 4 + r);
#pragma unroll
        for (int df = 0; df < 4; ++df) {
            o[df][0] *= al[0]; o[df][1] *= al[1];
            o[df][2] *= al[2]; o[df][3] *= al[3];
        }
        __syncthreads();

        // O += P V
#pragma unroll
        for (int c = 0; c < 2; ++c) {
            s8v pa = *(const s8v*)&Pl[w][lr][c * 32 + lg * 8];
#pragma unroll
            for (int df = 0; df < 4; ++df) {
                s8v vb = *(const s8v*)&Vl[df * 16 + lr][c * 32 + lg * 8];
                o[df] = __builtin_amdgcn_mfma_f32_16x16x32_bf16(pa, vb, o[df], 0, 0, 0);
            }
        }
    }

    float il[4];
#pragma unroll
    for (int r = 0; r < 4; ++r) il[r] = 1.0f / __shfl(l_run, lg * 4 + r);
#pragma unroll
    for (int df = 0; df < 4; ++df)
#pragma unroll
        for (int r = 0; r < 4; ++r)
            out[(size_t)(bb * Lx + q0 + w * 16 + lg * 4 + r) * Cx + h * 64 + df * 16 + lr] =
                f2bf(o[df][r] * il[r]);
}

// ---------------- bias table transpose: [D][NREL][H] -> [D][H][NREL] ---------
__global__ void transpose_bt_k(const float* __restrict__ bt, float* __restrict__ dst,
                               int H, int n)
{
    const int id = blockIdx.x * 256 + threadIdx.x;
    if (id >= n) return;
    const int rel = id % NREL;
    const int dh  = id / NREL;
    const int h   = dh % H;
    const int d   = dh / H;
    dst[id] = bt[((size_t)d * NREL + rel) * H + h];
}

// ---------------- LayerNorm: fp32 in, bf16 out -------------------------------
__global__ __launch_bounds__(256)
void ln_k(const float* __restrict__ x, const float* __restrict__ g,
          const float* __restrict__ be, short* __restrict__ y, int C)
{
    const int row = blockIdx.x;
    const float* xr = x + (size_t)row * C;
    float s = 0.f, ss = 0.f;
    for (int c = threadIdx.x; c < C; c += 256) { const float v = xr[c]; s += v; ss += v * v; }
#pragma unroll
    for (int off = 1; off < 64; off <<= 1) { s += __shfl_xor(s, off); ss += __shfl_xor(ss, off); }
    __shared__ float rs[4], rss[4];
    const int w = threadIdx.x >> 6;
    if ((threadIdx.x & 63) == 0) { rs[w] = s; rss[w] = ss; }
    __syncthreads();
    s  = rs[0] + rs[1] + rs[2] + rs[3];
    ss = rss[0] + rss[1] + rss[2] + rss[3];
    const float mean = s / C;
    const float rstd = rsqrtf(ss / C - mean * mean + 1e-5f);
    short* yr = y + (size_t)row * C;
    for (int c = threadIdx.x; c < C; c += 256)
        yr[c] = f2bf((xr[c] - mean) * rstd * g[c] + be[c]);
}

// ---------------- glue kernels ----------------------------------------------
__global__ void gather_tokens_k(const float* __restrict__ x, const int* __restrict__ vis,
                                short* __restrict__ tok)
{
    const int id = blockIdx.x * 256 + threadIdx.x;
    const int ti = id & 127;
    const int j  = (id >> 7) & 511;
    const int b  = id >> 16;
    const int ll = vis[j];
    const int hp = ll >> 5, wp = ll & 31;
    const int pi = ti >> 4, pj = (ti >> 1) & 7, ch = ti & 1;
    tok[id] = f2bf(x[(((size_t)(b * 2 + ch) * 256) + hp * 8 + pi) * 256 + wp * 8 + pj]);
}

__global__ void add_pos_vis_k(float* __restrict__ y, const float* __restrict__ pos,
                              const int* __restrict__ vis)
{
    const int id = blockIdx.x * 256 + threadIdx.x;
    const int c = id % 768;
    const int j = (id / 768) & 511;
    y[id] += pos[(size_t)vis[j] * 768 + c];
}

__global__ void fill_dec_k(float* __restrict__ y, const float* __restrict__ mtok,
                           const float* __restrict__ pos)
{
    const int id = blockIdx.x * 256 + threadIdx.x;
    const int c = id & 511;
    const int ll = (id >> 9) & 1023;
    y[id] = mtok[c] + pos[(ll << 9) + c];
}

__global__ void scatter_vis_k(float* __restrict__ y, const short* __restrict__ dvis,
                              const float* __restrict__ pos, const int* __restrict__ vis)
{
    const int id = blockIdx.x * 256 + threadIdx.x;
    const int c = id & 511;
    const int j = (id >> 9) & 511;
    const int b = id >> 18;
    const int ll = vis[j];
    y[(((size_t)b * 1024 + ll) << 9) + c] = bf2f(dvis[id]) + pos[(ll << 9) + c];
}

__global__ void concat_heads_k(const float* __restrict__ hmw, const float* __restrict__ hlw,
                               const float* __restrict__ hmb, const float* __restrict__ hlb,
                               float* __restrict__ hw2, float* __restrict__ hb2)
{
    const int id = blockIdx.x * 256 + threadIdx.x;   // 128*512
    const int col = id & 511, row = id >> 9;
    hw2[id] = row < 64 ? hmw[row * 512 + col] : hlw[(row - 64) * 512 + col];
    if (id < 128) hb2[id] = id < 64 ? hmb[id] : hlb[id - 64];
}

__global__ void unpatch2_k(const float* __restrict__ ht, float* __restrict__ out_mu,
                           float* __restrict__ out_lv)
{
    const int id = blockIdx.x * 256 + threadIdx.x;   // NB*65536
    const int j = id & 255, i = (id >> 8) & 255, b = id >> 16;
    const int hp = i >> 3, pi = i & 7, wp = j >> 3, pj = j & 7;
    const size_t tok = (size_t)b * 1024 + hp * 32 + wp;
    const int col = pi * 8 + pj;
    out_mu[id] = ht[tok * 128 + col];
    float v = ht[tok * 128 + 64 + col];
    out_lv[id] = fminf(6.0f, fmaxf(-6.0f, v));
}

__global__ void mask_fill_k(float* m) { m[blockIdx.x * 256 + threadIdx.x] = 1.0f; }

__global__ void mask_zero_k(float* m, const int* __restrict__ vis)
{
    const int id = blockIdx.x * 256 + threadIdx.x;
    const int b = id >> 9, j = id & 511;
    m[b * 1024 + vis[j]] = 0.0f;
}

// ---------------- launcher ---------------------------------------------------
extern "C" void kernel_launch(void* const* d_in, const int* in_sizes, int n_in,
                              void* d_out, int out_size, void* d_ws, size_t ws_size,
                              hipStream_t stream)
{
    const float* x       = (const float*)d_in[0];
    const int*   vis     = (const int*  )d_in[1];
    const float* eew     = (const float*)d_in[2];
    const float* eeb     = (const float*)d_in[3];
    const float* pos_enc = (const float*)d_in[4];
    const float* e_ln1s  = (const float*)d_in[5];
    const float* e_ln1b  = (const float*)d_in[6];
    const float* e_qkvw  = (const float*)d_in[7];
    const float* e_qkvb  = (const float*)d_in[8];
    const float* e_bt    = (const float*)d_in[9];
    const float* e_pw    = (const float*)d_in[10];
    const float* e_pb    = (const float*)d_in[11];
    const float* e_ln2s  = (const float*)d_in[12];
    const float* e_ln2b  = (const float*)d_in[13];
    const float* e_f1w   = (const float*)d_in[14];
    const float* e_f1b   = (const float*)d_in[15];
    const float* e_f2w   = (const float*)d_in[16];
    const float* e_f2b   = (const float*)d_in[17];
    const float* d_ln1s  = (const float*)d_in[18];
    const float* d_ln1b  = (const float*)d_in[19];
    const float* d_qkvw  = (const float*)d_in[20];
    const float* d_qkvb  = (const float*)d_in[21];
    const float* d_bt    = (const float*)d_in[22];
    const float* d_pw    = (const float*)d_in[23];
    const float* d_pb    = (const float*)d_in[24];
    const float* d_ln2s  = (const float*)d_in[25];
    const float* d_ln2b  = (const float*)d_in[26];
    const float* d_f1w   = (const float*)d_in[27];
    const float* d_f1b   = (const float*)d_in[28];
    const float* d_f2w   = (const float*)d_in[29];
    const float* d_f2b   = (const float*)d_in[30];
    const float* en_s    = (const float*)d_in[31];
    const float* en_b    = (const float*)d_in[32];
    const float* dew     = (const float*)d_in[33];
    const float* deb     = (const float*)d_in[34];
    const float* mtok    = (const float*)d_in[35];
    const float* pos_dec = (const float*)d_in[36];
    const float* dn_s    = (const float*)d_in[37];
    const float* dn_b    = (const float*)d_in[38];
    const float* hmw     = (const float*)d_in[39];
    const float* hmb     = (const float*)d_in[40];
    const float* hlw     = (const float*)d_in[41];
    const float* hlb     = (const float*)d_in[42];
    (void)in_sizes; (void)n_in; (void)out_size; (void)ws_size;

    char* base = (char*)d_ws;
    float* bx    = (float*)(base);                            // residual fp32  <=16.8MB
    short* bh    = (short*)(base + 17u * 1024 * 1024);        // LN out bf16    <=8.4MB
    short* batt  = (short*)(base + 26u * 1024 * 1024);        // attn/dec_vis   <=8.4MB
    short* bbig  = (short*)(base + 35u * 1024 * 1024);        // qkv/hid/tok    <=33.6MB
    float* ht    = (float*)(base + 69u * 1024 * 1024);        // head out fp32  4.2MB
    float* hw2   = (float*)(base + 74u * 1024 * 1024);        // fused head W   256KB
    float* hb2   = (float*)(base + 75u * 1024 * 1024);        // fused head b   512B
    float* btt_e = (float*)(base + 76u * 1024 * 1024);        // 1.15MB
    float* btt_d = (float*)(base + 78u * 1024 * 1024);        // 0.51MB

    // ---- one-time per launch: bias-table transposes + fused head weights ----
    transpose_bt_k<<<(6 * 12 * NREL + 255) / 256, 256, 0, stream>>>(e_bt, btt_e, 12, 6 * 12 * NREL);
    transpose_bt_k<<<(4 * 8 * NREL + 255) / 256, 256, 0, stream>>>(d_bt, btt_d, 8, 4 * 8 * NREL);
    concat_heads_k<<<256, 256, 0, stream>>>(hmw, hlw, hmb, hlb, hw2, hb2);

    // ---- patchify(visible) + encoder embed + pos ----
    gather_tokens_k<<<NB * LVIS * 128 / 256, 256, 0, stream>>>(x, vis, bbig);
    gemm_a16<0, false, false><<<dim3(6, 32), 256, 0, stream>>>(bbig, eew, eeb, nullptr, bx, 4096, 768, 128);
    add_pos_vis_k<<<NB * LVIS * 768 / 256, 256, 0, stream>>>(bx, pos_enc, vis);

    // ---- encoder blocks ----
    for (int d = 0; d < 6; ++d) {
        ln_k<<<4096, 256, 0, stream>>>(bx, e_ln1s + d * 768, e_ln1b + d * 768, bh, 768);
        gemm_a16<0, true, false><<<dim3(18, 32), 256, 0, stream>>>(bh, e_qkvw + (size_t)d * 2304 * 768,
                                                                   e_qkvb + d * 2304, nullptr, bbig, 4096, 2304, 768);
        attn_v2<true><<<dim3(8, 12, NB), 256, 0, stream>>>(bbig, btt_e + (size_t)d * 12 * NREL,
                                                           vis, batt, 512, 768);
        gemm_a16<1, false, false><<<dim3(6, 32), 256, 0, stream>>>(batt, e_pw + (size_t)d * 768 * 768,
                                                                   e_pb + d * 768, bx, bx, 4096, 768, 768);
        ln_k<<<4096, 256, 0, stream>>>(bx, e_ln2s + d * 768, e_ln2b + d * 768, bh, 768);
        gemm_a16<2, true, false><<<dim3(24, 32), 256, 0, stream>>>(bh, e_f1w + (size_t)d * 3072 * 768,
                                                                   e_f1b + d * 3072, nullptr, bbig, 4096, 3072, 768);
        prefill_k<<<4096 * 768 / 256, 256, 0, stream>>>(bx, e_f2b + d * 768, 768, 4096 * 768);
        gemm_a16<0, false, true><<<dim3(6, 32, 4), 256, 0, stream>>>(bbig, e_f2w + (size_t)d * 768 * 3072,
                                                                     nullptr, nullptr, bx, 4096, 768, 3072);
    }

    // ---- encoder norm + decoder embed + sequence build ----
    ln_k<<<4096, 256, 0, stream>>>(bx, en_s, en_b, bh, 768);
    gemm_a16<0, true, false><<<dim3(4, 32), 256, 0, stream>>>(bh, dew, deb, nullptr, batt, 4096, 512, 768);
    fill_dec_k<<<NB * LFULL * 512 / 256, 256, 0, stream>>>(bx, mtok, pos_dec);
    scatter_vis_k<<<NB * LVIS * 512 / 256, 256, 0, stream>>>(bx, batt, pos_dec, vis);

    // ---- decoder blocks ----
    for (int d = 0; d < 4; ++d) {
        ln_k<<<8192, 256, 0, stream>>>(bx, d_ln1s + d * 512, d_ln1b + d * 512, bh, 512);
        gemm_a16<0, true, false><<<dim3(12, 64), 256, 0, stream>>>(bh, d_qkvw + (size_t)d * 1536 * 512,
                                                                   d_qkvb + d * 1536, nullptr, bbig, 8192, 1536, 512);
        attn_v2<false><<<dim3(16, 8, NB), 256, 0, stream>>>(bbig, btt_d + (size_t)d * 8 * NREL,
                                                            nullptr, batt, 1024, 512);
        gemm_a16<1, false, false><<<dim3(4, 64), 256, 0, stream>>>(batt, d_pw + (size_t)d * 512 * 512,
                                                                   d_pb + d * 512, bx, bx, 8192, 512, 512);
        ln_k<<<8192, 256, 0, stream>>>(bx, d_ln2s + d * 512, d_ln2b + d * 512, bh, 512);
        gemm_a16<2, true, false><<<dim3(16, 64), 256, 0, stream>>>(bh, d_f1w + (size_t)d * 2048 * 512,
                                                                   d_f1b + d * 2048, nullptr, bbig, 8192, 2048, 512);
        prefill_k<<<8192 * 512 / 256, 256, 0, stream>>>(bx, d_f2b + d * 512, 512, 8192 * 512);
        gemm_a16<0, false, true><<<dim3(4, 64, 4), 256, 0, stream>>>(bbig, d_f2w + (size_t)d * 512 * 2048,
                                                                     nullptr, nullptr, bx, 8192, 512, 2048);
    }

    // ---- final norm + fused heads + unpatchify + mask ----
    ln_k<<<8192, 256, 0, stream>>>(bx, dn_s, dn_b, bh, 512);
    gemm_a16<0, false, false><<<dim3(1, 64), 256, 0, stream>>>(bh, hw2, hb2, nullptr, ht, 8192, 128, 512);

    float* out = (float*)d_out;
    unpatch2_k<<<NB * 65536 / 256, 256, 0, stream>>>(ht, out, out + 524288);
    mask_fill_k<<<32, 256, 0, stream>>>(out + 1048576);
    mask_zero_k<<<16, 256, 0, stream>>>(out + 1048576, vis);
}

// Round 7
// 2923.479 us; speedup vs baseline: 3.8228x; 1.1741x over previous
//
#include <hip/hip_runtime.h>
#include <hip/hip_bf16.h>
#include <math.h>

#define NB 8
#define NREL 3969

typedef __attribute__((ext_vector_type(8))) short s8v;
typedef __attribute__((ext_vector_type(4))) float f4v;

__device__ __forceinline__ float gelu_f(float x) {
    return 0.5f * x * (1.0f + erff(x * 0.7071067811865475f));
}
__device__ __forceinline__ short f2bf(float x) {
    __hip_bfloat16 h = __float2bfloat16(x);
    return __builtin_bit_cast(short, h);
}
__device__ __forceinline__ float bf2f(short s) {
    unsigned u = ((unsigned)(unsigned short)s) << 16;
    return __builtin_bit_cast(float, u);
}

// async global->LDS DMA, 16B per lane: LDS dest = base + lane*16 (HW rule)
__device__ __forceinline__ void gl_lds16(const void* g, void* l) {
    __builtin_amdgcn_global_load_lds(
        (const __attribute__((address_space(1))) void*)g,
        (__attribute__((address_space(3))) void*)l, 16, 0, 0);
}

// ============ GEMM v3 (m97 structure): C = A(M,K)bf16 @ W(N,K)^T bf16 ========
// MODE: 0 bias, 1 bias+residual(fp32), 2 bias+gelu.  OUTBF: bf16 out.
// 256 thr = 4 waves; 128x128 tile; BK=32; double-buffered global_load_lds
// staging into fragment-linear LDS (frag f, lane l <-> row f*16+(l&15),
// k-chunk (l>>4)*8).  One barrier per K-step.
template<int MODE, bool OUTBF>
__global__ __launch_bounds__(256)
void gemm_v3(const short* __restrict__ A, const short* __restrict__ W,
             const float* __restrict__ bias, const float* __restrict__ res,
             void* __restrict__ Cv, int M, int N, int K)
{
    __shared__ __align__(16) short Al[2][8][64][8];   // [buf][frag][lane][8]
    __shared__ __align__(16) short Wl[2][8][64][8];
    const int t  = threadIdx.x;
    const int w  = t >> 6, l = t & 63;
    const int lg = l >> 4, lr = l & 15;
    const int bm = blockIdx.y * 128, bn = blockIdx.x * 128;
    const int wm = (w & 1) * 64, wn = (w >> 1) * 64;

    f4v acc[4][4];
#pragma unroll
    for (int i = 0; i < 4; ++i)
#pragma unroll
        for (int j = 0; j < 4; ++j) acc[i][j] = (f4v){0.f, 0.f, 0.f, 0.f};

    // wave w stages A-frags {2w,2w+1} and W-frags {2w,2w+1}
    // lane l sources row (frag*16 + lr), k-chunk lg (8 bf16 = 16B)
    const short* pa0 = A + (size_t)(bm + w * 32 + lr) * K + lg * 8;
    const short* pa1 = pa0 + (size_t)16 * K;
    const short* pw0 = W + (size_t)(bn + w * 32 + lr) * K + lg * 8;
    const short* pw1 = pw0 + (size_t)16 * K;

    const int nt = K >> 5;
    int cur = 0;
    // prologue: stage tile 0 into buf 0
    gl_lds16(pa0, &Al[0][2 * w][0][0]);
    gl_lds16(pa1, &Al[0][2 * w + 1][0][0]);
    gl_lds16(pw0, &Wl[0][2 * w][0][0]);
    gl_lds16(pw1, &Wl[0][2 * w + 1][0][0]);
    __syncthreads();   // vmcnt(0) drain -> buf0 ready

    for (int ts = 0; ts < nt; ++ts) {
        if (ts + 1 < nt) {   // issue next tile's DMA, overlaps with compute
            const int k0 = (ts + 1) << 5;
            gl_lds16(pa0 + k0, &Al[cur ^ 1][2 * w][0][0]);
            gl_lds16(pa1 + k0, &Al[cur ^ 1][2 * w + 1][0][0]);
            gl_lds16(pw0 + k0, &Wl[cur ^ 1][2 * w][0][0]);
            gl_lds16(pw1 + k0, &Wl[cur ^ 1][2 * w + 1][0][0]);
        }
        s8v af[4], bf[4];
#pragma unroll
        for (int mi = 0; mi < 4; ++mi) af[mi] = *(const s8v*)&Al[cur][(wm >> 4) + mi][l][0];
#pragma unroll
        for (int ni = 0; ni < 4; ++ni) bf[ni] = *(const s8v*)&Wl[cur][(wn >> 4) + ni][l][0];
#pragma unroll
        for (int mi = 0; mi < 4; ++mi)
#pragma unroll
            for (int ni = 0; ni < 4; ++ni)
                acc[mi][ni] = __builtin_amdgcn_mfma_f32_16x16x32_bf16(af[mi], bf[ni], acc[mi][ni], 0, 0, 0);
        __syncthreads();   // drains DMA (next buf ready) + guards buf reuse
        cur ^= 1;
    }

    // epilogue: row = bm+wm+mi*16+lg*4+r, col = bn+wn+ni*16+lr
#pragma unroll
    for (int ni = 0; ni < 4; ++ni) {
        const int col = bn + wn + ni * 16 + lr;
        const float bb = bias[col];
#pragma unroll
        for (int mi = 0; mi < 4; ++mi)
#pragma unroll
            for (int r = 0; r < 4; ++r) {
                const int rowg = bm + wm + mi * 16 + lg * 4 + r;
                float v = acc[mi][ni][r] + bb;
                if (MODE == 1) v += res[(size_t)rowg * N + col];
                if (MODE == 2) v = gelu_f(v);
                if constexpr (OUTBF) ((short*)Cv)[(size_t)rowg * N + col] = f2bf(v);
                else                 ((float*)Cv)[(size_t)rowg * N + col] = v;
            }
    }
}

// ---------------- weight convert: up to 4 fp32 arrays -> one bf16 buffer -----
// all n multiples of 8; total = n0+n1+n2+n3
__global__ void cvt4_k(const float* __restrict__ p0, int n0,
                       const float* __restrict__ p1, int n1,
                       const float* __restrict__ p2, int n2,
                       const float* __restrict__ p3, int n3,
                       short* __restrict__ out, int total)
{
    int idx = (blockIdx.x * 256 + threadIdx.x) * 8;
    if (idx >= total) return;
    const float* src; int off = idx;
    if (off < n0) src = p0;
    else if ((off -= n0) < n1) src = p1;
    else if ((off -= n1) < n2) src = p2;
    else { off -= n2; src = p3; }
    const float4 a = *(const float4*)(src + off);
    const float4 b = *(const float4*)(src + off + 4);
    s8v v;
    v[0] = f2bf(a.x); v[1] = f2bf(a.y); v[2] = f2bf(a.z); v[3] = f2bf(a.w);
    v[4] = f2bf(b.x); v[5] = f2bf(b.y); v[6] = f2bf(b.z); v[7] = f2bf(b.w);
    *(s8v*)(out + idx) = v;
}

// ============ MFMA flash attention: swapped QK^T, lane-local softmax =========
template<bool HAS_IDX>
__global__ __launch_bounds__(256)
void attn_v2(const short* __restrict__ qkv, const float* __restrict__ btt,
             const int* vis, short* __restrict__ out, int Lx, int Cx)
{
    __shared__ __align__(16) short Kl[64][72];
    __shared__ __align__(16) short Vl[64][72];
    __shared__ __align__(16) short Pl[4][16][72];
    __shared__ int qpos[64];
    __shared__ int kpos[64];

    const int q0 = blockIdx.x * 64;
    const int h  = blockIdx.y, bb = blockIdx.z;
    const int t  = threadIdx.x;
    const int w  = t >> 6, l = t & 63;
    const int lg = l >> 4, lr = l & 15;
    const int C3 = 3 * Cx;
    const float* bth = btt + (size_t)h * NREL;

    s8v qa[2];
    {
        const short* src = qkv + (size_t)(bb * Lx + q0 + w * 16 + lr) * C3 + h * 64 + lg * 8;
        qa[0] = *(const s8v*)(src);
        qa[1] = *(const s8v*)(src + 32);
    }
    int qi, qj;
    if (HAS_IDX) {
        if (t < 64) qpos[t] = vis[q0 + t];
        __syncthreads();
        const int qv = qpos[w * 16 + lr];
        qi = qv >> 5; qj = qv & 31;
    } else {
        const int qv = q0 + w * 16 + lr;
        qi = qv >> 5; qj = qv & 31;
    }

    float m_run = -INFINITY, l_run = 0.0f;
    f4v o[4];
#pragma unroll
    for (int df = 0; df < 4; ++df) o[df] = (f4v){0.f, 0.f, 0.f, 0.f};

    const int nt = Lx >> 6;
    for (int kt = 0; kt < nt; ++kt) {
        __syncthreads();
        {
            const int key = t >> 2, dh = (t & 3) * 16;
            const short* src = qkv + (size_t)(bb * Lx + kt * 64 + key) * C3 + Cx + h * 64 + dh;
            *(s8v*)&Kl[key][dh]     = *(const s8v*)(src);
            *(s8v*)&Kl[key][dh + 8] = *(const s8v*)(src + 8);
        }
        {
            const int key = t & 63, dh = (t >> 6) * 16;
            const short* src = qkv + (size_t)(bb * Lx + kt * 64 + key) * C3 + 2 * Cx + h * 64 + dh;
            const s8v v0 = *(const s8v*)(src);
            const s8v v1 = *(const s8v*)(src + 8);
#pragma unroll
            for (int e = 0; e < 8; ++e) Vl[dh + e][key] = v0[e];
#pragma unroll
            for (int e = 0; e < 8; ++e) Vl[dh + 8 + e][key] = v1[e];
        }
        if (HAS_IDX && t < 64) kpos[t] = vis[kt * 64 + t];
        __syncthreads();

        f4v st[4];
#pragma unroll
        for (int f = 0; f < 4; ++f) {
            st[f] = (f4v){0.f, 0.f, 0.f, 0.f};
#pragma unroll
            for (int c = 0; c < 2; ++c) {
                s8v ka = *(const s8v*)&Kl[f * 16 + lr][c * 32 + lg * 8];
                st[f] = __builtin_amdgcn_mfma_f32_16x16x32_bf16(ka, qa[c], st[f], 0, 0, 0);
            }
        }

        float sv[16];
        if (HAS_IDX) {
#pragma unroll
            for (int f = 0; f < 4; ++f)
#pragma unroll
                for (int r = 0; r < 4; ++r) {
                    const int kv = kpos[f * 16 + lg * 4 + r];
                    const int rel = (qi - (kv >> 5) + 31) * 63 + (qj - (kv & 31) + 31);
                    sv[f * 4 + r] = st[f][r] * 0.125f + bth[rel];
                }
        } else {
#pragma unroll
            for (int f = 0; f < 4; ++f) {
                const int kbase = kt * 64 + f * 16 + lg * 4;
                const int R0 = (qi - (kbase >> 5) + 31) * 63 + (qj - (kbase & 31) + 31);
#pragma unroll
                for (int r = 0; r < 4; ++r)
                    sv[f * 4 + r] = st[f][r] * 0.125f + bth[R0 - r];
            }
        }

        float mx = sv[0];
#pragma unroll
        for (int i = 1; i < 16; ++i) mx = fmaxf(mx, sv[i]);
        mx = fmaxf(mx, __shfl_xor(mx, 16));
        mx = fmaxf(mx, __shfl_xor(mx, 32));
        const float mnew = fmaxf(m_run, mx);
        const float alpha = __expf(m_run - mnew);
        float rs = 0.0f;
#pragma unroll
        for (int i = 0; i < 16; ++i) { sv[i] = __expf(sv[i] - mnew); rs += sv[i]; }
        rs += __shfl_xor(rs, 16);
        rs += __shfl_xor(rs, 32);
        l_run = l_run * alpha + rs;
        m_run = mnew;

#pragma unroll
        for (int f = 0; f < 4; ++f) {
            short4 p4;
            p4.x = f2bf(sv[f * 4 + 0]); p4.y = f2bf(sv[f * 4 + 1]);
            p4.z = f2bf(sv[f * 4 + 2]); p4.w = f2bf(sv[f * 4 + 3]);
            *(short4*)&Pl[w][lr][f * 16 + lg * 4] = p4;
        }

        float al[4];
#pragma unroll
        for (int r = 0; r < 4; ++r) al[r] = __shfl(alpha, lg * 4 + r);
#pragma unroll
        for (int df = 0; df < 4; ++df) {
            o[df][0] *= al[0]; o[df][1] *= al[1];
            o[df][2] *= al[2]; o[df][3] *= al[3];
        }
        __syncthreads();

#pragma unroll
        for (int c = 0; c < 2; ++c) {
            s8v pa = *(const s8v*)&Pl[w][lr][c * 32 + lg * 8];
#pragma unroll
            for (int df = 0; df < 4; ++df) {
                s8v vb = *(const s8v*)&Vl[df * 16 + lr][c * 32 + lg * 8];
                o[df] = __builtin_amdgcn_mfma_f32_16x16x32_bf16(pa, vb, o[df], 0, 0, 0);
            }
        }
    }

    float il[4];
#pragma unroll
    for (int r = 0; r < 4; ++r) il[r] = 1.0f / __shfl(l_run, lg * 4 + r);
#pragma unroll
    for (int df = 0; df < 4; ++df)
#pragma unroll
        for (int r = 0; r < 4; ++r)
            out[(size_t)(bb * Lx + q0 + w * 16 + lg * 4 + r) * Cx + h * 64 + df * 16 + lr] =
                f2bf(o[df][r] * il[r]);
}

// ---------------- bias table transpose: [D][NREL][H] -> [D][H][NREL] ---------
__global__ void transpose_bt_k(const float* __restrict__ bt, float* __restrict__ dst,
                               int H, int n)
{
    const int id = blockIdx.x * 256 + threadIdx.x;
    if (id >= n) return;
    const int rel = id % NREL;
    const int dh  = id / NREL;
    const int h   = dh % H;
    const int d   = dh / H;
    dst[id] = bt[((size_t)d * NREL + rel) * H + h];
}

// ---------------- LayerNorm: fp32 in, bf16 out -------------------------------
__global__ __launch_bounds__(256)
void ln_k(const float* __restrict__ x, const float* __restrict__ g,
          const float* __restrict__ be, short* __restrict__ y, int C)
{
    const int row = blockIdx.x;
    const float* xr = x + (size_t)row * C;
    float s = 0.f, ss = 0.f;
    for (int c = threadIdx.x; c < C; c += 256) { const float v = xr[c]; s += v; ss += v * v; }
#pragma unroll
    for (int off = 1; off < 64; off <<= 1) { s += __shfl_xor(s, off); ss += __shfl_xor(ss, off); }
    __shared__ float rs[4], rss[4];
    const int w = threadIdx.x >> 6;
    if ((threadIdx.x & 63) == 0) { rs[w] = s; rss[w] = ss; }
    __syncthreads();
    s  = rs[0] + rs[1] + rs[2] + rs[3];
    ss = rss[0] + rss[1] + rss[2] + rss[3];
    const float mean = s / C;
    const float rstd = rsqrtf(ss / C - mean * mean + 1e-5f);
    short* yr = y + (size_t)row * C;
    for (int c = threadIdx.x; c < C; c += 256)
        yr[c] = f2bf((xr[c] - mean) * rstd * g[c] + be[c]);
}

// ---------------- glue kernels ----------------------------------------------
__global__ void gather_tokens_k(const float* __restrict__ x, const int* __restrict__ vis,
                                short* __restrict__ tok)
{
    const int id = blockIdx.x * 256 + threadIdx.x;
    const int ti = id & 127;
    const int j  = (id >> 7) & 511;
    const int b  = id >> 16;
    const int ll = vis[j];
    const int hp = ll >> 5, wp = ll & 31;
    const int pi = ti >> 4, pj = (ti >> 1) & 7, ch = ti & 1;
    tok[id] = f2bf(x[(((size_t)(b * 2 + ch) * 256) + hp * 8 + pi) * 256 + wp * 8 + pj]);
}

__global__ void add_pos_vis_k(float* __restrict__ y, const float* __restrict__ pos,
                              const int* __restrict__ vis)
{
    const int id = blockIdx.x * 256 + threadIdx.x;
    const int c = id % 768;
    const int j = (id / 768) & 511;
    y[id] += pos[(size_t)vis[j] * 768 + c];
}

__global__ void fill_dec_k(float* __restrict__ y, const float* __restrict__ mtok,
                           const float* __restrict__ pos)
{
    const int id = blockIdx.x * 256 + threadIdx.x;
    const int c = id & 511;
    const int ll = (id >> 9) & 1023;
    y[id] = mtok[c] + pos[(ll << 9) + c];
}

__global__ void scatter_vis_k(float* __restrict__ y, const short* __restrict__ dvis,
                              const float* __restrict__ pos, const int* __restrict__ vis)
{
    const int id = blockIdx.x * 256 + threadIdx.x;
    const int c = id & 511;
    const int j = (id >> 9) & 511;
    const int b = id >> 18;
    const int ll = vis[j];
    y[(((size_t)b * 1024 + ll) << 9) + c] = bf2f(dvis[id]) + pos[(ll << 9) + c];
}

__global__ void concat_heads_k(const float* __restrict__ hmw, const float* __restrict__ hlw,
                               const float* __restrict__ hmb, const float* __restrict__ hlb,
                               short* __restrict__ hw2, float* __restrict__ hb2)
{
    const int id = blockIdx.x * 256 + threadIdx.x;   // 128*512
    const int col = id & 511, row = id >> 9;
    hw2[id] = f2bf(row < 64 ? hmw[row * 512 + col] : hlw[(row - 64) * 512 + col]);
    if (id < 128) hb2[id] = id < 64 ? hmb[id] : hlb[id - 64];
}

__global__ void unpatch2_k(const float* __restrict__ ht, float* __restrict__ out_mu,
                           float* __restrict__ out_lv)
{
    const int id = blockIdx.x * 256 + threadIdx.x;   // NB*65536
    const int j = id & 255, i = (id >> 8) & 255, b = id >> 16;
    const int hp = i >> 3, pi = i & 7, wp = j >> 3, pj = j & 7;
    const size_t tok = (size_t)b * 1024 + hp * 32 + wp;
    const int col = pi * 8 + pj;
    out_mu[id] = ht[tok * 128 + col];
    float v = ht[tok * 128 + 64 + col];
    out_lv[id] = fminf(6.0f, fmaxf(-6.0f, v));
}

__global__ void mask_fill_k(float* m) { m[blockIdx.x * 256 + threadIdx.x] = 1.0f; }

__global__ void mask_zero_k(float* m, const int* __restrict__ vis)
{
    const int id = blockIdx.x * 256 + threadIdx.x;
    const int b = id >> 9, j = id & 511;
    m[b * 1024 + vis[j]] = 0.0f;
}

// ---------------- launcher ---------------------------------------------------
extern "C" void kernel_launch(void* const* d_in, const int* in_sizes, int n_in,
                              void* d_out, int out_size, void* d_ws, size_t ws_size,
                              hipStream_t stream)
{
    const float* x       = (const float*)d_in[0];
    const int*   vis     = (const int*  )d_in[1];
    const float* eew     = (const float*)d_in[2];
    const float* eeb     = (const float*)d_in[3];
    const float* pos_enc = (const float*)d_in[4];
    const float* e_ln1s  = (const float*)d_in[5];
    const float* e_ln1b  = (const float*)d_in[6];
    const float* e_qkvw  = (const float*)d_in[7];
    const float* e_qkvb  = (const float*)d_in[8];
    const float* e_bt    = (const float*)d_in[9];
    const float* e_pw    = (const float*)d_in[10];
    const float* e_pb    = (const float*)d_in[11];
    const float* e_ln2s  = (const float*)d_in[12];
    const float* e_ln2b  = (const float*)d_in[13];
    const float* e_f1w   = (const float*)d_in[14];
    const float* e_f1b   = (const float*)d_in[15];
    const float* e_f2w   = (const float*)d_in[16];
    const float* e_f2b   = (const float*)d_in[17];
    const float* d_ln1s  = (const float*)d_in[18];
    const float* d_ln1b  = (const float*)d_in[19];
    const float* d_qkvw  = (const float*)d_in[20];
    const float* d_qkvb  = (const float*)d_in[21];
    const float* d_bt    = (const float*)d_in[22];
    const float* d_pw    = (const float*)d_in[23];
    const float* d_pb    = (const float*)d_in[24];
    const float* d_ln2s  = (const float*)d_in[25];
    const float* d_ln2b  = (const float*)d_in[26];
    const float* d_f1w   = (const float*)d_in[27];
    const float* d_f1b   = (const float*)d_in[28];
    const float* d_f2w   = (const float*)d_in[29];
    const float* d_f2b   = (const float*)d_in[30];
    const float* en_s    = (const float*)d_in[31];
    const float* en_b    = (const float*)d_in[32];
    const float* dew     = (const float*)d_in[33];
    const float* deb     = (const float*)d_in[34];
    const float* mtok    = (const float*)d_in[35];
    const float* pos_dec = (const float*)d_in[36];
    const float* dn_s    = (const float*)d_in[37];
    const float* dn_b    = (const float*)d_in[38];
    const float* hmw     = (const float*)d_in[39];
    const float* hmb     = (const float*)d_in[40];
    const float* hlw     = (const float*)d_in[41];
    const float* hlb     = (const float*)d_in[42];
    (void)in_sizes; (void)n_in; (void)out_size; (void)ws_size;

    char* base = (char*)d_ws;
    float* bx    = (float*)(base);                              // residual fp32  16.8MB
    short* bh    = (short*)(base + 17ull * 1024 * 1024);        // LN out bf16    8.4MB
    short* batt  = (short*)(base + 26ull * 1024 * 1024);        // attn/dec_vis   8.4MB
    short* bbig  = (short*)(base + 35ull * 1024 * 1024);        // qkv/hid/tok    33.6MB
    short* wb    = (short*)(base + 69ull * 1024 * 1024);        // layer W bf16   14.2MB
    short* wsm   = (short*)(base + 84ull * 1024 * 1024);        // small W bf16   1.2MB
    float* hb2   = (float*)(base + 86ull * 1024 * 1024);        // fused head b
    float* ht    = (float*)(base + 87ull * 1024 * 1024);        // head out fp32  4.2MB
    float* btt_e = (float*)(base + 92ull * 1024 * 1024);        // 1.15MB
    float* btt_d = (float*)(base + 94ull * 1024 * 1024);        // 0.51MB

    short* eewb = wsm;                 // 98304
    short* dewb = wsm + 98304;         // 393216
    short* hw2b = wsm + 491520;        // 65536

    // ---- one-time per launch: tables + small weight converts ----
    transpose_bt_k<<<(6 * 12 * NREL + 255) / 256, 256, 0, stream>>>(e_bt, btt_e, 12, 6 * 12 * NREL);
    transpose_bt_k<<<(4 * 8 * NREL + 255) / 256, 256, 0, stream>>>(d_bt, btt_d, 8, 4 * 8 * NREL);
    concat_heads_k<<<256, 256, 0, stream>>>(hmw, hlw, hmb, hlb, hw2b, hb2);
    cvt4_k<<<240, 256, 0, stream>>>(eew, 98304, dew, 393216, eew, 0, eew, 0, wsm, 491520);

    // ---- patchify(visible) + encoder embed + pos ----
    gather_tokens_k<<<NB * 512 * 128 / 256, 256, 0, stream>>>(x, vis, bbig);
    gemm_v3<0, false><<<dim3(6, 32), 256, 0, stream>>>(bbig, eewb, eeb, nullptr, bx, 4096, 768, 128);
    add_pos_vis_k<<<NB * 512 * 768 / 256, 256, 0, stream>>>(bx, pos_enc, vis);

    // ---- encoder blocks ----
    for (int d = 0; d < 6; ++d) {
        cvt4_k<<<3456, 256, 0, stream>>>(e_qkvw + (size_t)d * 1769472, 1769472,
                                         e_pw   + (size_t)d * 589824,  589824,
                                         e_f1w  + (size_t)d * 2359296, 2359296,
                                         e_f2w  + (size_t)d * 2359296, 2359296, wb, 7077888);
        ln_k<<<4096, 256, 0, stream>>>(bx, e_ln1s + d * 768, e_ln1b + d * 768, bh, 768);
        gemm_v3<0, true><<<dim3(18, 32), 256, 0, stream>>>(bh, wb, e_qkvb + d * 2304,
                                                           nullptr, bbig, 4096, 2304, 768);
        attn_v2<true><<<dim3(8, 12, NB), 256, 0, stream>>>(bbig, btt_e + (size_t)d * 12 * NREL,
                                                           vis, batt, 512, 768);
        gemm_v3<1, false><<<dim3(6, 32), 256, 0, stream>>>(batt, wb + 1769472, e_pb + d * 768,
                                                           bx, bx, 4096, 768, 768);
        ln_k<<<4096, 256, 0, stream>>>(bx, e_ln2s + d * 768, e_ln2b + d * 768, bh, 768);
        gemm_v3<2, true><<<dim3(24, 32), 256, 0, stream>>>(bh, wb + 2359296, e_f1b + d * 3072,
                                                           nullptr, bbig, 4096, 3072, 768);
        gemm_v3<1, false><<<dim3(6, 32), 256, 0, stream>>>(bbig, wb + 4718592, e_f2b + d * 768,
                                                           bx, bx, 4096, 768, 3072);
    }

    // ---- encoder norm + decoder embed + sequence build ----
    ln_k<<<4096, 256, 0, stream>>>(bx, en_s, en_b, bh, 768);
    gemm_v3<0, true><<<dim3(4, 32), 256, 0, stream>>>(bh, dewb, deb, nullptr, batt, 4096, 512, 768);
    fill_dec_k<<<NB * 1024 * 512 / 256, 256, 0, stream>>>(bx, mtok, pos_dec);
    scatter_vis_k<<<NB * 512 * 512 / 256, 256, 0, stream>>>(bx, batt, pos_dec, vis);

    // ---- decoder blocks ----
    for (int d = 0; d < 4; ++d) {
        cvt4_k<<<1536, 256, 0, stream>>>(d_qkvw + (size_t)d * 786432,  786432,
                                         d_pw   + (size_t)d * 262144,  262144,
                                         d_f1w  + (size_t)d * 1048576, 1048576,
                                         d_f2w  + (size_t)d * 1048576, 1048576, wb, 3145728);
        ln_k<<<8192, 256, 0, stream>>>(bx, d_ln1s + d * 512, d_ln1b + d * 512, bh, 512);
        gemm_v3<0, true><<<dim3(12, 64), 256, 0, stream>>>(bh, wb, d_qkvb + d * 1536,
                                                           nullptr, bbig, 8192, 1536, 512);
        attn_v2<false><<<dim3(16, 8, NB), 256, 0, stream>>>(bbig, btt_d + (size_t)d * 8 * NREL,
                                                            nullptr, batt, 1024, 512);
        gemm_v3<1, false><<<dim3(4, 64), 256, 0, stream>>>(batt, wb + 786432, d_pb + d * 512,
                                                           bx, bx, 8192, 512, 512);
        ln_k<<<8192, 256, 0, stream>>>(bx, d_ln2s + d * 512, d_ln2b + d * 512, bh, 512);
        gemm_v3<2, true><<<dim3(16, 64), 256, 0, stream>>>(bh, wb + 1048576, d_f1b + d * 2048,
                                                           nullptr, bbig, 8192, 2048, 512);
        gemm_v3<1, false><<<dim3(4, 64), 256, 0, stream>>>(bbig, wb + 2097152, d_f2b + d * 512,
                                                           bx, bx, 8192, 512, 2048);
    }

    // ---- final norm + fused heads + unpatchify + mask ----
    ln_k<<<8192, 256, 0, stream>>>(bx, dn_s, dn_b, bh, 512);
    gemm_v3<0, false><<<dim3(1, 64), 256, 0, stream>>>(bh, hw2b, hb2, nullptr, ht, 8192, 128, 512);

    float* out = (float*)d_out;
    unpatch2_k<<<NB * 65536 / 256, 256, 0, stream>>>(ht, out, out + 524288);
    mask_fill_k<<<32, 256, 0, stream>>>(out + 1048576);
    mask_zero_k<<<16, 256, 0, stream>>>(out + 1048576, vis);
}